// Round 3
// baseline (498.222 us; speedup 1.0000x reference)
//
#include <hip/hip_runtime.h>
#include <hip/hip_bf16.h>
#include <math.h>

typedef __hip_bfloat16 bf16;
typedef __attribute__((ext_vector_type(8))) short short8;
typedef __attribute__((ext_vector_type(4))) float f32x4;

#define T_DIM 2048
#define C_DIM 1024
#define NHEAD 16
#define HS 64

__device__ __forceinline__ short bfbits(float x) {
    bf16 h = __float2bfloat16(x);
    return *reinterpret_cast<short*>(&h);
}
__device__ __forceinline__ float bf2f(bf16 x) { return __bfloat162float(x); }

// Split 8 consecutive floats into bf16 hi + bf16 lo (residual) short8s.
__device__ __forceinline__ void split8(const float* p, short8& h, short8& l) {
    float4 f0 = reinterpret_cast<const float4*>(p)[0];
    float4 f1 = reinterpret_cast<const float4*>(p)[1];
    float vals[8] = {f0.x, f0.y, f0.z, f0.w, f1.x, f1.y, f1.z, f1.w};
#pragma unroll
    for (int j = 0; j < 8; ++j) {
        bf16 hb = __float2bfloat16(vals[j]);
        float r = vals[j] - __bfloat162float(hb);
        h[j] = *reinterpret_cast<short*>(&hb);
        bf16 lb = __float2bfloat16(r);
        l[j] = *reinterpret_cast<short*>(&lb);
    }
}

// ---------------------------------------------------------------------------
// Split-precision GEMM: C[M,N] = act(A[M,K] @ B[N,K]^T + bias), fp32 in/out.
// Each operand split into bf16 hi+lo; 3 MFMA passes => ~fp32 accuracy.
// 128x128 tile, BK=64, 4 waves.
// ---------------------------------------------------------------------------
__global__ __launch_bounds__(256) void gemm_split_kernel(
    const float* __restrict__ A, const float* __restrict__ B,
    const float* __restrict__ bias, float* __restrict__ C,
    int M, int N, int K, int act)
{
    __shared__ bf16 Ah[128][64], Al[128][64], Bh[128][64], Bl[128][64];
    const int tid = threadIdx.x;
    const int lane = tid & 63, wid = tid >> 6;
    const int wr = wid >> 1, wc = wid & 1;
    const int m0 = blockIdx.y * 128, n0 = blockIdx.x * 128;

    f32x4 acc[4][4] = {};
    const int nK = K >> 6;
    for (int kt = 0; kt < nK; ++kt) {
        const int k0 = kt << 6;
#pragma unroll
        for (int i = 0; i < 4; ++i) {
            int cc = tid + i * 256;
            int row = cc >> 3, off = (cc & 7) << 3;
            short8 h8, l8;
            split8(&A[(long)(m0 + row) * K + k0 + off], h8, l8);
            *reinterpret_cast<short8*>(&Ah[row][off]) = h8;
            *reinterpret_cast<short8*>(&Al[row][off]) = l8;
            split8(&B[(long)(n0 + row) * K + k0 + off], h8, l8);
            *reinterpret_cast<short8*>(&Bh[row][off]) = h8;
            *reinterpret_cast<short8*>(&Bl[row][off]) = l8;
        }
        __syncthreads();
#pragma unroll
        for (int kk = 0; kk < 2; ++kk) {
            short8 afh[4], afl[4], bfh[4], bfl[4];
#pragma unroll
            for (int t = 0; t < 4; ++t) {
                int r = t * 16 + (lane & 15), cbase = kk * 32 + (lane >> 4) * 8;
                afh[t] = *reinterpret_cast<const short8*>(&Ah[wr * 64 + r][cbase]);
                afl[t] = *reinterpret_cast<const short8*>(&Al[wr * 64 + r][cbase]);
                bfh[t] = *reinterpret_cast<const short8*>(&Bh[wc * 64 + r][cbase]);
                bfl[t] = *reinterpret_cast<const short8*>(&Bl[wc * 64 + r][cbase]);
            }
#pragma unroll
            for (int tm = 0; tm < 4; ++tm)
#pragma unroll
                for (int tn = 0; tn < 4; ++tn) {
                    acc[tm][tn] = __builtin_amdgcn_mfma_f32_16x16x32_bf16(
                        afh[tm], bfh[tn], acc[tm][tn], 0, 0, 0);
                    acc[tm][tn] = __builtin_amdgcn_mfma_f32_16x16x32_bf16(
                        afh[tm], bfl[tn], acc[tm][tn], 0, 0, 0);
                    acc[tm][tn] = __builtin_amdgcn_mfma_f32_16x16x32_bf16(
                        afl[tm], bfh[tn], acc[tm][tn], 0, 0, 0);
                }
        }
        __syncthreads();
    }
#pragma unroll
    for (int tm = 0; tm < 4; ++tm)
#pragma unroll
        for (int tn = 0; tn < 4; ++tn)
#pragma unroll
            for (int r = 0; r < 4; ++r) {
                int row = m0 + wr * 64 + tm * 16 + (lane >> 4) * 4 + r;
                int col = n0 + wc * 64 + tn * 16 + (lane & 15);
                float v = acc[tm][tn][r];
                if (bias) v += bias[col];
                if (act == 1) v = v > 0.f ? v + 1.f : __expf(v);
                C[(long)row * N + col] = v;
            }
}

// ---------------------------------------------------------------------------
// Fused QKV split-precision GEMM. blockIdx.x in [0,24): 8 n-blocks per proj.
// proj 0 -> Wq (phi), 1 -> Wk (phi), 2 -> Wv (none). C = qkv + proj*2M floats.
// ---------------------------------------------------------------------------
__global__ __launch_bounds__(256) void qkv_split_kernel(
    const float* __restrict__ A, const float* __restrict__ Wq,
    const float* __restrict__ Wk, const float* __restrict__ Wv,
    float* __restrict__ qkv)
{
    __shared__ bf16 Ah[128][64], Al[128][64], Bh[128][64], Bl[128][64];
    const int tid = threadIdx.x;
    const int lane = tid & 63, wid = tid >> 6;
    const int wr = wid >> 1, wc = wid & 1;
    const int proj = blockIdx.x >> 3;
    const int n0 = (blockIdx.x & 7) * 128;
    const int m0 = blockIdx.y * 128;
    const float* B = proj == 0 ? Wq : (proj == 1 ? Wk : Wv);
    float* C = qkv + (long)proj * 2097152;
    const int K = 1024, N = 1024;
    const int act = proj < 2 ? 1 : 0;

    f32x4 acc[4][4] = {};
    for (int kt = 0; kt < 16; ++kt) {
        const int k0 = kt << 6;
#pragma unroll
        for (int i = 0; i < 4; ++i) {
            int cc = tid + i * 256;
            int row = cc >> 3, off = (cc & 7) << 3;
            short8 h8, l8;
            split8(&A[(long)(m0 + row) * K + k0 + off], h8, l8);
            *reinterpret_cast<short8*>(&Ah[row][off]) = h8;
            *reinterpret_cast<short8*>(&Al[row][off]) = l8;
            split8(&B[(long)(n0 + row) * K + k0 + off], h8, l8);
            *reinterpret_cast<short8*>(&Bh[row][off]) = h8;
            *reinterpret_cast<short8*>(&Bl[row][off]) = l8;
        }
        __syncthreads();
#pragma unroll
        for (int kk = 0; kk < 2; ++kk) {
            short8 afh[4], afl[4], bfh[4], bfl[4];
#pragma unroll
            for (int t = 0; t < 4; ++t) {
                int r = t * 16 + (lane & 15), cbase = kk * 32 + (lane >> 4) * 8;
                afh[t] = *reinterpret_cast<const short8*>(&Ah[wr * 64 + r][cbase]);
                afl[t] = *reinterpret_cast<const short8*>(&Al[wr * 64 + r][cbase]);
                bfh[t] = *reinterpret_cast<const short8*>(&Bh[wc * 64 + r][cbase]);
                bfl[t] = *reinterpret_cast<const short8*>(&Bl[wc * 64 + r][cbase]);
            }
#pragma unroll
            for (int tm = 0; tm < 4; ++tm)
#pragma unroll
                for (int tn = 0; tn < 4; ++tn) {
                    acc[tm][tn] = __builtin_amdgcn_mfma_f32_16x16x32_bf16(
                        afh[tm], bfh[tn], acc[tm][tn], 0, 0, 0);
                    acc[tm][tn] = __builtin_amdgcn_mfma_f32_16x16x32_bf16(
                        afh[tm], bfl[tn], acc[tm][tn], 0, 0, 0);
                    acc[tm][tn] = __builtin_amdgcn_mfma_f32_16x16x32_bf16(
                        afl[tm], bfh[tn], acc[tm][tn], 0, 0, 0);
                }
        }
        __syncthreads();
    }
#pragma unroll
    for (int tm = 0; tm < 4; ++tm)
#pragma unroll
        for (int tn = 0; tn < 4; ++tn)
#pragma unroll
            for (int r = 0; r < 4; ++r) {
                int row = m0 + wr * 64 + tm * 16 + (lane >> 4) * 4 + r;
                int col = n0 + wc * 64 + tn * 16 + (lane & 15);
                float v = acc[tm][tn][r];
                if (act == 1) v = v > 0.f ? v + 1.f : __expf(v);
                C[(long)row * N + col] = v;
            }
}

// ---------------------------------------------------------------------------
// Per (block b, head h): W_all[s,i] = sum_j OP[s,j] * Wmap[i,j] via split
// MFMA. Chunk c covers j = c*64 + e (d = c). OP[s][e] = k[s][c]*v[s][e],
// split exactly into bf16 hi+lo. Wmap chunks split too. fp32 cumsum -> tails.
// ---------------------------------------------------------------------------
__global__ __launch_bounds__(256) void setfeat_kernel(
    const float* __restrict__ kbuf, const float* __restrict__ vbuf,
    const float* __restrict__ Wkmap, const float* __restrict__ Wvmap,
    const float* __restrict__ bkmap, const float* __restrict__ bvmap,
    float* __restrict__ Ktail, float* __restrict__ Vtail,
    float* __restrict__ Kset, float* __restrict__ Vset)
{
    __shared__ char smem[65536];
    float(*vblk)[64] = reinterpret_cast<float(*)[64]>(smem);           // 16KB
    bf16(*OPh)[64] = reinterpret_cast<bf16(*)[64]>(smem + 16384);
    bf16(*OPl)[64] = reinterpret_cast<bf16(*)[64]>(smem + 24576);
    bf16(*Wkh)[64] = reinterpret_cast<bf16(*)[64]>(smem + 32768);
    bf16(*Wkl)[64] = reinterpret_cast<bf16(*)[64]>(smem + 40960);
    bf16(*Wvh)[64] = reinterpret_cast<bf16(*)[64]>(smem + 49152);
    bf16(*Wvl)[64] = reinterpret_cast<bf16(*)[64]>(smem + 57344);
    float(*WallK)[64] = reinterpret_cast<float(*)[64]>(smem + 16384);  // reuse
    float(*WallV)[64] = reinterpret_cast<float(*)[64]>(smem + 32768);  // reuse

    const int tid = threadIdx.x;
    const int lane = tid & 63, wid = tid >> 6;
    const int wr = wid >> 1, wc = wid & 1;
    const int b = blockIdx.x >> 4, h = blockIdx.x & 15;
    const long base_kv = ((long)b * 64) * C_DIM + h * HS;

    {   // stage v block fp32: 64x64
        int row = tid >> 2, c0 = (tid & 3) * 16;
        const float4* src = reinterpret_cast<const float4*>(&vbuf[base_kv + (long)row * C_DIM + c0]);
        float4* dst = reinterpret_cast<float4*>(&vblk[row][c0]);
#pragma unroll
        for (int j = 0; j < 4; ++j) dst[j] = src[j];
    }
    __syncthreads();

    f32x4 accK[2][2] = {}, accV[2][2] = {};
    for (int c = 0; c < 64; ++c) {
        {   // stage Wk/Wv chunk (64 rows x 64 cols), split hi/lo
            int row = tid >> 2, c0 = (tid & 3) * 16;
            const float* pk = &Wkmap[(long)row * 4096 + c * 64 + c0];
            const float* pv = &Wvmap[(long)row * 4096 + c * 64 + c0];
            short8 h8, l8;
            split8(pk, h8, l8);
            *reinterpret_cast<short8*>(&Wkh[row][c0]) = h8;
            *reinterpret_cast<short8*>(&Wkl[row][c0]) = l8;
            split8(pk + 8, h8, l8);
            *reinterpret_cast<short8*>(&Wkh[row][c0 + 8]) = h8;
            *reinterpret_cast<short8*>(&Wkl[row][c0 + 8]) = l8;
            split8(pv, h8, l8);
            *reinterpret_cast<short8*>(&Wvh[row][c0]) = h8;
            *reinterpret_cast<short8*>(&Wvl[row][c0]) = l8;
            split8(pv + 8, h8, l8);
            *reinterpret_cast<short8*>(&Wvh[row][c0 + 8]) = h8;
            *reinterpret_cast<short8*>(&Wvl[row][c0 + 8]) = l8;
        }
        {   // build OP chunk: OP[s][e] = k[s][c] * v[s][e], exact hi/lo split
            int s = tid >> 2, e0 = (tid & 3) * 16;
            float kc = kbuf[base_kv + (long)s * C_DIM + c];
#pragma unroll
            for (int g = 0; g < 2; ++g) {
                short8 h8, l8;
#pragma unroll
                for (int j = 0; j < 8; ++j) {
                    float p = kc * vblk[s][e0 + g * 8 + j];
                    bf16 hb = __float2bfloat16(p);
                    float r = p - __bfloat162float(hb);
                    h8[j] = *reinterpret_cast<short*>(&hb);
                    bf16 lb = __float2bfloat16(r);
                    l8[j] = *reinterpret_cast<short*>(&lb);
                }
                *reinterpret_cast<short8*>(&OPh[s][e0 + g * 8]) = h8;
                *reinterpret_cast<short8*>(&OPl[s][e0 + g * 8]) = l8;
            }
        }
        __syncthreads();
#pragma unroll
        for (int kk = 0; kk < 2; ++kk) {
            short8 ah[2], al[2], bkh[2], bkl[2], bvh[2], bvl[2];
#pragma unroll
            for (int t = 0; t < 2; ++t) {
                int r = t * 16 + (lane & 15), cbase = kk * 32 + (lane >> 4) * 8;
                ah[t] = *reinterpret_cast<const short8*>(&OPh[wr * 32 + r][cbase]);
                al[t] = *reinterpret_cast<const short8*>(&OPl[wr * 32 + r][cbase]);
                bkh[t] = *reinterpret_cast<const short8*>(&Wkh[wc * 32 + r][cbase]);
                bkl[t] = *reinterpret_cast<const short8*>(&Wkl[wc * 32 + r][cbase]);
                bvh[t] = *reinterpret_cast<const short8*>(&Wvh[wc * 32 + r][cbase]);
                bvl[t] = *reinterpret_cast<const short8*>(&Wvl[wc * 32 + r][cbase]);
            }
#pragma unroll
            for (int tm = 0; tm < 2; ++tm)
#pragma unroll
                for (int tn = 0; tn < 2; ++tn) {
                    accK[tm][tn] = __builtin_amdgcn_mfma_f32_16x16x32_bf16(
                        ah[tm], bkh[tn], accK[tm][tn], 0, 0, 0);
                    accK[tm][tn] = __builtin_amdgcn_mfma_f32_16x16x32_bf16(
                        ah[tm], bkl[tn], accK[tm][tn], 0, 0, 0);
                    accK[tm][tn] = __builtin_amdgcn_mfma_f32_16x16x32_bf16(
                        al[tm], bkh[tn], accK[tm][tn], 0, 0, 0);
                    accV[tm][tn] = __builtin_amdgcn_mfma_f32_16x16x32_bf16(
                        ah[tm], bvh[tn], accV[tm][tn], 0, 0, 0);
                    accV[tm][tn] = __builtin_amdgcn_mfma_f32_16x16x32_bf16(
                        ah[tm], bvl[tn], accV[tm][tn], 0, 0, 0);
                    accV[tm][tn] = __builtin_amdgcn_mfma_f32_16x16x32_bf16(
                        al[tm], bvh[tn], accV[tm][tn], 0, 0, 0);
                }
        }
        __syncthreads();
    }
#pragma unroll
    for (int tm = 0; tm < 2; ++tm)
#pragma unroll
        for (int tn = 0; tn < 2; ++tn)
#pragma unroll
            for (int r = 0; r < 4; ++r) {
                int row = wr * 32 + tm * 16 + (lane >> 4) * 4 + r;
                int col = wc * 32 + tn * 16 + (lane & 15);
                WallK[row][col] = accK[tm][tn][r];
                WallV[row][col] = accV[tm][tn][r];
            }
    __syncthreads();
    if (tid < 128) {
        int i = tid & 63;
        bool isV = tid >= 64;
        const float bi = isV ? bvmap[i] : bkmap[i];
        float run = 0.f;
        for (int s = 0; s < 64; ++s) {
            run += isV ? WallV[s][i] : WallK[s][i];
            float val = run + bi;
            long t = (long)b * 64 + s;
            if (isV) Vtail[t * C_DIM + h * HS + i] = val;
            else     Ktail[t * C_DIM + h * HS + i] = val;
            if (s == 63) {
                if (isV) Vset[(b * NHEAD + h) * HS + i] = val;
                else     Kset[(b * NHEAD + h) * HS + i] = val;
            }
        }
    }
}

// ---------------------------------------------------------------------------
// Attention: one wave per (t,h). Lane s<nb: set logit; lane nb: tail logit.
// Softmax across the wave, then lane d accumulates output dim d. All fp32.
// ---------------------------------------------------------------------------
__global__ __launch_bounds__(256) void attn_kernel(
    const float* __restrict__ qbuf, const float* __restrict__ Kset,
    const float* __restrict__ Vset, const float* __restrict__ Ktail,
    const float* __restrict__ Vtail, float* __restrict__ attout)
{
    __shared__ float qsh[4][64];
    __shared__ float attsh[4][64];
    const int tid = threadIdx.x, lane = tid & 63, wid = tid >> 6;
    const int g = blockIdx.x * 4 + wid;
    const int t = g >> 4, h = g & 15;
    const int nb = t >> 6;
    const float scale = 0.125f;
    const long qoff = (long)t * C_DIM + h * HS;
    qsh[wid][lane] = qbuf[qoff + lane];
    __syncthreads();
    float logit = -INFINITY;
    if (lane < nb) {
        float s = 0.f;
        const float* Kp = &Kset[(lane * NHEAD + h) * HS];
        for (int d = 0; d < 64; ++d) s += qsh[wid][d] * Kp[d];
        logit = s * scale;
    } else if (lane == nb) {
        float s = 0.f;
        const float* Kp = &Ktail[qoff];
        for (int d = 0; d < 64; ++d) s += qsh[wid][d] * Kp[d];
        logit = s * scale;
    }
    float m = logit;
    for (int off = 32; off; off >>= 1) m = fmaxf(m, __shfl_xor(m, off, 64));
    float e = (lane <= nb) ? __expf(logit - m) : 0.f;
    float sum = e;
    for (int off = 32; off; off >>= 1) sum += __shfl_xor(sum, off, 64);
    attsh[wid][lane] = e / sum;
    __syncthreads();
    float out = 0.f;
    for (int s = 0; s < nb; ++s)
        out += attsh[wid][s] * Vset[(s * NHEAD + h) * HS + lane];
    out += attsh[wid][nb] * Vtail[qoff + lane];
    attout[qoff + lane] = out;
}

// ---------------------------------------------------------------------------
extern "C" void kernel_launch(void* const* d_in, const int* in_sizes, int n_in,
                              void* d_out, int out_size, void* d_ws, size_t ws_size,
                              hipStream_t stream)
{
    const float* x     = (const float*)d_in[0];
    const float* Wq    = (const float*)d_in[1];
    const float* Wk    = (const float*)d_in[2];
    const float* Wv    = (const float*)d_in[3];
    const float* Wkmap = (const float*)d_in[4];
    const float* bkmap = (const float*)d_in[5];
    const float* Wvmap = (const float*)d_in[6];
    const float* bvmap = (const float*)d_in[7];
    const float* Wc    = (const float*)d_in[8];
    const float* bc    = (const float*)d_in[9];
    float* out = (float*)d_out;

    char* ws = (char*)d_ws;
    float* qkv    = (float*)(ws);                 // q,k,v each 2048*1024 fp32 (8MB), contiguous
    float* q      = qkv;
    float* k      = qkv + 2097152;
    float* v      = qkv + 2 * 2097152;
    float* Ktail  = (float*)(ws + (3l << 23));
    float* Vtail  = (float*)(ws + (4l << 23));
    float* attout = (float*)(ws + (5l << 23));
    float* Kset   = (float*)(ws + (6l << 23));
    float* Vset   = (float*)(ws + (6l << 23) + (1l << 18));

    qkv_split_kernel<<<dim3(24, 16), 256, 0, stream>>>(x, Wq, Wk, Wv, qkv);
    setfeat_kernel<<<512, 256, 0, stream>>>(k, v, Wkmap, Wvmap, bkmap, bvmap,
                                            Ktail, Vtail, Kset, Vset);
    attn_kernel<<<8192, 256, 0, stream>>>(q, Kset, Vset, Ktail, Vtail, attout);
    gemm_split_kernel<<<dim3(8, 16), 256, 0, stream>>>(attout, Wc, bc, out, 2048, 1024, 1024, 0);
}

// Round 5
// 361.160 us; speedup vs baseline: 1.3795x; 1.3795x over previous
//
#include <hip/hip_runtime.h>
#include <hip/hip_bf16.h>
#include <math.h>

typedef __hip_bfloat16 bf16;
typedef __attribute__((ext_vector_type(8))) short short8;
typedef __attribute__((ext_vector_type(4))) float f32x4;

#define C_DIM 1024
#define NHEAD 16
#define HS 64

__device__ __forceinline__ float bf2f(bf16 x) { return __bfloat162float(x); }

// Split 8 consecutive floats into bf16 hi + bf16 lo (residual) short8s.
__device__ __forceinline__ void split8(const float* p, short8& h, short8& l) {
    float4 f0 = reinterpret_cast<const float4*>(p)[0];
    float4 f1 = reinterpret_cast<const float4*>(p)[1];
    float vals[8] = {f0.x, f0.y, f0.z, f0.w, f1.x, f1.y, f1.z, f1.w};
#pragma unroll
    for (int j = 0; j < 8; ++j) {
        bf16 hb = __float2bfloat16(vals[j]);
        float r = vals[j] - __bfloat162float(hb);
        h[j] = *reinterpret_cast<short*>(&hb);
        bf16 lb = __float2bfloat16(r);
        l[j] = *reinterpret_cast<short*>(&lb);
    }
}

// [rows][64] bf16 tile (128B rows, 8x16B chunks/row), XOR-swizzled: ch ^= row&7.
// Swizzle applied identically on write and read -> bijective, conflict-free
// fragment reads (16 lanes/quarter hit all 8 chunk slots).
__device__ __forceinline__ short8* tchunk(bf16* tile, int row, int ch) {
    return reinterpret_cast<short8*>(tile + row * 64 + (((ch) ^ (row & 7)) << 3));
}
// fp32 [64][64] tile, 32B groups (8/row), grp ^= row&7, half selects float4.
__device__ __forceinline__ float4* vgrp(float* v, int row, int grp, int half) {
    return reinterpret_cast<float4*>(v + row * 64 + ((grp ^ (row & 7)) << 3) + (half << 2));
}

// ---------------------------------------------------------------------------
// Fused QKV split-precision GEMM. blockIdx.x in [0,24): 8 n-blocks per proj.
// proj 0 -> Wq (phi), 1 -> Wk (phi), 2 -> Wv (none). 128x128 tile, BK=64.
// ---------------------------------------------------------------------------
__global__ __launch_bounds__(256) void qkv_split_kernel(
    const float* __restrict__ A, const float* __restrict__ Wq,
    const float* __restrict__ Wk, const float* __restrict__ Wv,
    float* __restrict__ qkv)
{
    __shared__ bf16 Ah[8192], Al[8192], Bh[8192], Bl[8192];
    const int tid = threadIdx.x;
    const int lane = tid & 63, wid = tid >> 6;
    const int wr = wid >> 1, wc = wid & 1;
    const int proj = blockIdx.x >> 3;
    const int n0 = (blockIdx.x & 7) * 128;
    const int m0 = blockIdx.y * 128;
    const float* B = proj == 0 ? Wq : (proj == 1 ? Wk : Wv);
    float* C = qkv + (long)proj * 2097152;
    const int K = 1024, N = 1024;

    f32x4 acc[4][4] = {};
    for (int kt = 0; kt < 16; ++kt) {
        const int k0 = kt << 6;
#pragma unroll
        for (int i = 0; i < 4; ++i) {
            int cc = tid + i * 256;
            int row = cc >> 3, ch = cc & 7;
            short8 h8, l8;
            split8(&A[(long)(m0 + row) * K + k0 + ch * 8], h8, l8);
            *tchunk(Ah, row, ch) = h8;
            *tchunk(Al, row, ch) = l8;
            split8(&B[(long)(n0 + row) * K + k0 + ch * 8], h8, l8);
            *tchunk(Bh, row, ch) = h8;
            *tchunk(Bl, row, ch) = l8;
        }
        __syncthreads();
#pragma unroll
        for (int kk = 0; kk < 2; ++kk) {
            short8 afh[4], afl[4], bfh[4], bfl[4];
#pragma unroll
            for (int t = 0; t < 4; ++t) {
                int ra = wr * 64 + t * 16 + (lane & 15);
                int rb = wc * 64 + t * 16 + (lane & 15);
                int ch = kk * 4 + (lane >> 4);
                afh[t] = *tchunk(Ah, ra, ch);
                afl[t] = *tchunk(Al, ra, ch);
                bfh[t] = *tchunk(Bh, rb, ch);
                bfl[t] = *tchunk(Bl, rb, ch);
            }
#pragma unroll
            for (int tm = 0; tm < 4; ++tm)
#pragma unroll
                for (int tn = 0; tn < 4; ++tn) {
                    acc[tm][tn] = __builtin_amdgcn_mfma_f32_16x16x32_bf16(
                        afh[tm], bfh[tn], acc[tm][tn], 0, 0, 0);
                    acc[tm][tn] = __builtin_amdgcn_mfma_f32_16x16x32_bf16(
                        afh[tm], bfl[tn], acc[tm][tn], 0, 0, 0);
                    acc[tm][tn] = __builtin_amdgcn_mfma_f32_16x16x32_bf16(
                        afl[tm], bfh[tn], acc[tm][tn], 0, 0, 0);
                }
        }
        __syncthreads();
    }
#pragma unroll
    for (int tm = 0; tm < 4; ++tm)
#pragma unroll
        for (int tn = 0; tn < 4; ++tn)
#pragma unroll
            for (int r = 0; r < 4; ++r) {
                int row = m0 + wr * 64 + tm * 16 + (lane >> 4) * 4 + r;
                int col = n0 + wc * 64 + tn * 16 + (lane & 15);
                float v = acc[tm][tn][r];
                if (proj < 2) v = v > 0.f ? v + 1.f : __expf(v);
                C[(long)row * N + col] = v;
            }
}

// ---------------------------------------------------------------------------
// Per (block b, head h): W_all[s,i] = sum_j OP[s,j]*Wmap[i,j], split MFMA.
// Chunk c: OP[s][e] = k[s][c]*v[s][e] (exact hi/lo split of fp32 product).
// All LDS tiles XOR-swizzled. fp32 cumsum -> tails; row 63 -> set features.
// ---------------------------------------------------------------------------
__global__ __launch_bounds__(256) void setfeat_kernel(
    const float* __restrict__ kbuf, const float* __restrict__ vbuf,
    const float* __restrict__ Wkmap, const float* __restrict__ Wvmap,
    const float* __restrict__ bkmap, const float* __restrict__ bvmap,
    float* __restrict__ Ktail, float* __restrict__ Vtail,
    float* __restrict__ Kset, float* __restrict__ Vset)
{
    __shared__ char smem[65536];
    float* vblk = reinterpret_cast<float*>(smem);                    // 16KB [64][64] f32 swz
    bf16* OPh = reinterpret_cast<bf16*>(smem + 16384);               // 8KB each
    bf16* OPl = reinterpret_cast<bf16*>(smem + 24576);
    bf16* Wkh = reinterpret_cast<bf16*>(smem + 32768);
    bf16* Wkl = reinterpret_cast<bf16*>(smem + 40960);
    bf16* Wvh = reinterpret_cast<bf16*>(smem + 49152);
    bf16* Wvl = reinterpret_cast<bf16*>(smem + 57344);
    float(*WallK)[64] = reinterpret_cast<float(*)[64]>(smem + 16384);  // overlay
    float(*WallV)[64] = reinterpret_cast<float(*)[64]>(smem + 32768);  // overlay

    const int tid = threadIdx.x;
    const int lane = tid & 63, wid = tid >> 6;
    const int wr = wid >> 1, wc = wid & 1;
    const int b = blockIdx.x >> 4, h = blockIdx.x & 15;
    const long base_kv = ((long)b * 64) * C_DIM + h * HS;

    {   // stage v block fp32 (swizzled 32B groups)
        int row = tid >> 2, tg = tid & 3;
        const float* src = &vbuf[base_kv + (long)row * C_DIM + tg * 16];
#pragma unroll
        for (int j = 0; j < 2; ++j)
#pragma unroll
            for (int hf = 0; hf < 2; ++hf)
                *vgrp(vblk, row, tg * 2 + j, hf) =
                    *reinterpret_cast<const float4*>(src + j * 8 + hf * 4);
    }
    __syncthreads();

    f32x4 accK[2][2] = {}, accV[2][2] = {};
    for (int c = 0; c < 64; ++c) {
        {   // stage Wk/Wv chunk (64x64 fp32 -> hi/lo bf16), swizzled
            int row = tid >> 2, tg = tid & 3;
            const float* pk = &Wkmap[(long)row * 4096 + c * 64 + tg * 16];
            const float* pv = &Wvmap[(long)row * 4096 + c * 64 + tg * 16];
            short8 h8, l8;
            split8(pk, h8, l8);
            *tchunk(Wkh, row, tg * 2) = h8;  *tchunk(Wkl, row, tg * 2) = l8;
            split8(pk + 8, h8, l8);
            *tchunk(Wkh, row, tg * 2 + 1) = h8;  *tchunk(Wkl, row, tg * 2 + 1) = l8;
            split8(pv, h8, l8);
            *tchunk(Wvh, row, tg * 2) = h8;  *tchunk(Wvl, row, tg * 2) = l8;
            split8(pv + 8, h8, l8);
            *tchunk(Wvh, row, tg * 2 + 1) = h8;  *tchunk(Wvl, row, tg * 2 + 1) = l8;
        }
        {   // build OP chunk: OP[s][e] = k[s][c]*v[s][e], exact hi/lo split
            int s = tid >> 2, tg = tid & 3;
            float kc = kbuf[base_kv + (long)s * C_DIM + c];
#pragma unroll
            for (int g = 0; g < 2; ++g) {
                float4 v0 = *vgrp(vblk, s, tg * 2 + g, 0);
                float4 v1 = *vgrp(vblk, s, tg * 2 + g, 1);
                float vv[8] = {v0.x, v0.y, v0.z, v0.w, v1.x, v1.y, v1.z, v1.w};
                short8 h8, l8;
#pragma unroll
                for (int j = 0; j < 8; ++j) {
                    float p = kc * vv[j];
                    bf16 hb = __float2bfloat16(p);
                    float r = p - __bfloat162float(hb);
                    h8[j] = *reinterpret_cast<short*>(&hb);
                    bf16 lb = __float2bfloat16(r);
                    l8[j] = *reinterpret_cast<short*>(&lb);
                }
                *tchunk(OPh, s, tg * 2 + g) = h8;
                *tchunk(OPl, s, tg * 2 + g) = l8;
            }
        }
        __syncthreads();
#pragma unroll
        for (int kk = 0; kk < 2; ++kk) {
            short8 ah[2], al[2], bkh[2], bkl[2], bvh[2], bvl[2];
#pragma unroll
            for (int t = 0; t < 2; ++t) {
                int ra = wr * 32 + t * 16 + (lane & 15);
                int rb = wc * 32 + t * 16 + (lane & 15);
                int ch = kk * 4 + (lane >> 4);
                ah[t]  = *tchunk(OPh, ra, ch);
                al[t]  = *tchunk(OPl, ra, ch);
                bkh[t] = *tchunk(Wkh, rb, ch);
                bkl[t] = *tchunk(Wkl, rb, ch);
                bvh[t] = *tchunk(Wvh, rb, ch);
                bvl[t] = *tchunk(Wvl, rb, ch);
            }
#pragma unroll
            for (int tm = 0; tm < 2; ++tm)
#pragma unroll
                for (int tn = 0; tn < 2; ++tn) {
                    accK[tm][tn] = __builtin_amdgcn_mfma_f32_16x16x32_bf16(
                        ah[tm], bkh[tn], accK[tm][tn], 0, 0, 0);
                    accK[tm][tn] = __builtin_amdgcn_mfma_f32_16x16x32_bf16(
                        ah[tm], bkl[tn], accK[tm][tn], 0, 0, 0);
                    accK[tm][tn] = __builtin_amdgcn_mfma_f32_16x16x32_bf16(
                        al[tm], bkh[tn], accK[tm][tn], 0, 0, 0);
                    accV[tm][tn] = __builtin_amdgcn_mfma_f32_16x16x32_bf16(
                        ah[tm], bvh[tn], accV[tm][tn], 0, 0, 0);
                    accV[tm][tn] = __builtin_amdgcn_mfma_f32_16x16x32_bf16(
                        ah[tm], bvl[tn], accV[tm][tn], 0, 0, 0);
                    accV[tm][tn] = __builtin_amdgcn_mfma_f32_16x16x32_bf16(
                        al[tm], bvh[tn], accV[tm][tn], 0, 0, 0);
                }
        }
        __syncthreads();
    }
#pragma unroll
    for (int tm = 0; tm < 2; ++tm)
#pragma unroll
        for (int tn = 0; tn < 2; ++tn)
#pragma unroll
            for (int r = 0; r < 4; ++r) {
                int row = wr * 32 + tm * 16 + (lane >> 4) * 4 + r;
                int col = wc * 32 + tn * 16 + (lane & 15);
                WallK[row][col] = accK[tm][tn][r];
                WallV[row][col] = accV[tm][tn][r];
            }
    __syncthreads();
    if (tid < 128) {
        int i = tid & 63;
        bool isV = tid >= 64;
        const float bi = isV ? bvmap[i] : bkmap[i];
        float run = 0.f;
        for (int s = 0; s < 64; ++s) {
            run += isV ? WallV[s][i] : WallK[s][i];
            float val = run + bi;
            long t = (long)b * 64 + s;
            if (isV) Vtail[t * C_DIM + h * HS + i] = val;
            else     Ktail[t * C_DIM + h * HS + i] = val;
            if (s == 63) {
                if (isV) Vset[(b * NHEAD + h) * HS + i] = val;
                else     Kset[(b * NHEAD + h) * HS + i] = val;
            }
        }
    }
}

// ---------------------------------------------------------------------------
// Attention: one wave per (t,h). Lane s<nb: set logit; lane nb: tail logit.
// ---------------------------------------------------------------------------
__global__ __launch_bounds__(256) void attn_kernel(
    const float* __restrict__ qbuf, const float* __restrict__ Kset,
    const float* __restrict__ Vset, const float* __restrict__ Ktail,
    const float* __restrict__ Vtail, float* __restrict__ attout)
{
    __shared__ float qsh[4][64];
    __shared__ float attsh[4][64];
    const int tid = threadIdx.x, lane = tid & 63, wid = tid >> 6;
    const int g = blockIdx.x * 4 + wid;
    const int t = g >> 4, h = g & 15;
    const int nb = t >> 6;
    const float scale = 0.125f;
    const long qoff = (long)t * C_DIM + h * HS;
    qsh[wid][lane] = qbuf[qoff + lane];
    __syncthreads();
    float logit = -INFINITY;
    if (lane < nb) {
        float s = 0.f;
        const float* Kp = &Kset[(lane * NHEAD + h) * HS];
        for (int d = 0; d < 64; ++d) s += qsh[wid][d] * Kp[d];
        logit = s * scale;
    } else if (lane == nb) {
        float s = 0.f;
        const float* Kp = &Ktail[qoff];
        for (int d = 0; d < 64; ++d) s += qsh[wid][d] * Kp[d];
        logit = s * scale;
    }
    float m = logit;
    for (int off = 32; off; off >>= 1) m = fmaxf(m, __shfl_xor(m, off, 64));
    float e = (lane <= nb) ? __expf(logit - m) : 0.f;
    float sum = e;
    for (int off = 32; off; off >>= 1) sum += __shfl_xor(sum, off, 64);
    attsh[wid][lane] = e / sum;
    __syncthreads();
    float out = 0.f;
    for (int s = 0; s < nb; ++s)
        out += attsh[wid][s] * Vset[(s * NHEAD + h) * HS + lane];
    out += attsh[wid][nb] * Vtail[qoff + lane];
    attout[qoff + lane] = out;
}

// ---------------------------------------------------------------------------
// Final GEMM: out = attout @ Wc^T + bc. 128x64 tile (grid 16x16 = 256 blocks
// -> all CUs busy), BK=64, split-precision, swizzled LDS.
// ---------------------------------------------------------------------------
__global__ __launch_bounds__(256) void gemm_final_kernel(
    const float* __restrict__ A, const float* __restrict__ B,
    const float* __restrict__ bias, float* __restrict__ C)
{
    __shared__ bf16 Ah[8192], Al[8192], Bh[4096], Bl[4096];
    const int tid = threadIdx.x;
    const int lane = tid & 63, wid = tid >> 6;
    const int wr = wid >> 1, wc = wid & 1;
    const int m0 = blockIdx.y * 128, n0 = blockIdx.x * 64;
    const int K = 1024, N = 1024;

    f32x4 acc[4][2] = {};
    for (int kt = 0; kt < 16; ++kt) {
        const int k0 = kt << 6;
#pragma unroll
        for (int i = 0; i < 4; ++i) {
            int cc = tid + i * 256;
            int row = cc >> 3, ch = cc & 7;
            short8 h8, l8;
            split8(&A[(long)(m0 + row) * K + k0 + ch * 8], h8, l8);
            *tchunk(Ah, row, ch) = h8;
            *tchunk(Al, row, ch) = l8;
        }
#pragma unroll
        for (int i = 0; i < 2; ++i) {
            int cc = tid + i * 256;
            int row = cc >> 3, ch = cc & 7;
            short8 h8, l8;
            split8(&B[(long)(n0 + row) * K + k0 + ch * 8], h8, l8);
            *tchunk(Bh, row, ch) = h8;
            *tchunk(Bl, row, ch) = l8;
        }
        __syncthreads();
#pragma unroll
        for (int kk = 0; kk < 2; ++kk) {
            short8 afh[4], afl[4], bfh[2], bfl[2];
#pragma unroll
            for (int t = 0; t < 4; ++t) {
                int ra = wr * 64 + t * 16 + (lane & 15);
                int ch = kk * 4 + (lane >> 4);
                afh[t] = *tchunk(Ah, ra, ch);
                afl[t] = *tchunk(Al, ra, ch);
            }
#pragma unroll
            for (int t = 0; t < 2; ++t) {
                int rb = wc * 32 + t * 16 + (lane & 15);
                int ch = kk * 4 + (lane >> 4);
                bfh[t] = *tchunk(Bh, rb, ch);
                bfl[t] = *tchunk(Bl, rb, ch);
            }
#pragma unroll
            for (int tm = 0; tm < 4; ++tm)
#pragma unroll
                for (int tn = 0; tn < 2; ++tn) {
                    acc[tm][tn] = __builtin_amdgcn_mfma_f32_16x16x32_bf16(
                        afh[tm], bfh[tn], acc[tm][tn], 0, 0, 0);
                    acc[tm][tn] = __builtin_amdgcn_mfma_f32_16x16x32_bf16(
                        afh[tm], bfl[tn], acc[tm][tn], 0, 0, 0);
                    acc[tm][tn] = __builtin_amdgcn_mfma_f32_16x16x32_bf16(
                        afl[tm], bfh[tn], acc[tm][tn], 0, 0, 0);
                }
        }
        __syncthreads();
    }
#pragma unroll
    for (int tm = 0; tm < 4; ++tm)
#pragma unroll
        for (int tn = 0; tn < 2; ++tn)
#pragma unroll
            for (int r = 0; r < 4; ++r) {
                int row = m0 + wr * 64 + tm * 16 + (lane >> 4) * 4 + r;
                int col = n0 + wc * 32 + tn * 16 + (lane & 15);
                C[(long)row * N + col] = acc[tm][tn][r] + bias[col];
            }
}

// ---------------------------------------------------------------------------
extern "C" void kernel_launch(void* const* d_in, const int* in_sizes, int n_in,
                              void* d_out, int out_size, void* d_ws, size_t ws_size,
                              hipStream_t stream)
{
    const float* x     = (const float*)d_in[0];
    const float* Wq    = (const float*)d_in[1];
    const float* Wk    = (const float*)d_in[2];
    const float* Wv    = (const float*)d_in[3];
    const float* Wkmap = (const float*)d_in[4];
    const float* bkmap = (const float*)d_in[5];
    const float* Wvmap = (const float*)d_in[6];
    const float* bvmap = (const float*)d_in[7];
    const float* Wc    = (const float*)d_in[8];
    const float* bc    = (const float*)d_in[9];
    float* out = (float*)d_out;

    char* ws = (char*)d_ws;
    float* qkv    = (float*)(ws);                 // q,k,v each 2048*1024 fp32
    float* q      = qkv;
    float* k      = qkv + 2097152;
    float* v      = qkv + 2 * 2097152;
    float* Ktail  = (float*)(ws + (3l << 23));
    float* Vtail  = (float*)(ws + (4l << 23));
    float* attout = (float*)(ws + (5l << 23));
    float* Kset   = (float*)(ws + (6l << 23));
    float* Vset   = (float*)(ws + (6l << 23) + (1l << 18));

    qkv_split_kernel<<<dim3(24, 16), 256, 0, stream>>>(x, Wq, Wk, Wv, qkv);
    setfeat_kernel<<<512, 256, 0, stream>>>(k, v, Wkmap, Wvmap, bkmap, bvmap,
                                            Ktail, Vtail, Kset, Vset);
    attn_kernel<<<8192, 256, 0, stream>>>(q, Kset, Vset, Ktail, Vtail, attout);
    gemm_final_kernel<<<dim3(16, 16), 256, 0, stream>>>(attout, Wc, bc, out);
}

// Round 6
// 303.960 us; speedup vs baseline: 1.6391x; 1.1882x over previous
//
#include <hip/hip_runtime.h>
#include <hip/hip_bf16.h>
#include <math.h>

typedef __hip_bfloat16 bf16;
typedef __attribute__((ext_vector_type(8))) short short8;
typedef __attribute__((ext_vector_type(4))) float f32x4;

#define C_DIM 1024
#define NHEAD 16
#define HS 64

__device__ __forceinline__ float bf2f(bf16 x) { return __bfloat162float(x); }

// Split 8 consecutive floats into bf16 hi + bf16 lo (residual) short8s.
__device__ __forceinline__ void split8(const float* p, short8& h, short8& l) {
    float4 f0 = reinterpret_cast<const float4*>(p)[0];
    float4 f1 = reinterpret_cast<const float4*>(p)[1];
    float vals[8] = {f0.x, f0.y, f0.z, f0.w, f1.x, f1.y, f1.z, f1.w};
#pragma unroll
    for (int j = 0; j < 8; ++j) {
        bf16 hb = __float2bfloat16(vals[j]);
        float r = vals[j] - __bfloat162float(hb);
        h[j] = *reinterpret_cast<short*>(&hb);
        bf16 lb = __float2bfloat16(r);
        l[j] = *reinterpret_cast<short*>(&lb);
    }
}

// [rows][64] bf16 tile (128B rows, 8x16B chunks/row), XOR-swizzled: ch ^= row&7.
__device__ __forceinline__ short8* tchunk(bf16* tile, int row, int ch) {
    return reinterpret_cast<short8*>(tile + row * 64 + (((ch) ^ (row & 7)) << 3));
}

// ---------------------------------------------------------------------------
// Pre-split x, Wq, Wk, Wv (fp32 -> bf16 hi/lo). Grid 2560, 2048 elems/block.
// ---------------------------------------------------------------------------
__global__ __launch_bounds__(256) void presplit_all_kernel(
    const float* __restrict__ x, const float* __restrict__ Wq,
    const float* __restrict__ Wk, const float* __restrict__ Wv,
    bf16* __restrict__ xh, bf16* __restrict__ xl,
    bf16* __restrict__ wqh, bf16* __restrict__ wql,
    bf16* __restrict__ wkh, bf16* __restrict__ wkl,
    bf16* __restrict__ wvh, bf16* __restrict__ wvl)
{
    int blk = blockIdx.x;
    const float* src; bf16 *dh, *dl; long off;
    if (blk < 1024)      { src = x;  dh = xh;  dl = xl;  off = (long)blk * 2048; }
    else if (blk < 1536) { src = Wq; dh = wqh; dl = wql; off = (long)(blk - 1024) * 2048; }
    else if (blk < 2048) { src = Wk; dh = wkh; dl = wkl; off = (long)(blk - 1536) * 2048; }
    else                 { src = Wv; dh = wvh; dl = wvl; off = (long)(blk - 2048) * 2048; }
    long p = off + threadIdx.x * 8;
    short8 h8, l8;
    split8(&src[p], h8, l8);
    *reinterpret_cast<short8*>(&dh[p]) = h8;
    *reinterpret_cast<short8*>(&dl[p]) = l8;
}

// Pre-split Wc (runs after setfeat; its dest overlays Wm4). Grid 512.
__global__ __launch_bounds__(256) void presplit_wc_kernel(
    const float* __restrict__ Wc, bf16* __restrict__ wch, bf16* __restrict__ wcl)
{
    long p = (long)blockIdx.x * 2048 + threadIdx.x * 8;
    short8 h8, l8;
    split8(&Wc[p], h8, l8);
    *reinterpret_cast<short8*>(&wch[p]) = h8;
    *reinterpret_cast<short8*>(&wcl[p]) = l8;
}

// ---------------------------------------------------------------------------
// Pre-split Wkmap/Wvmap into chunk-major Wm4[d][part][row=i][e] bf16,
// part: 0=K_hi 1=K_lo 2=V_hi 3=V_lo. Grid 64 (one block per d).
// ---------------------------------------------------------------------------
__global__ __launch_bounds__(256) void presplit_wmap_kernel(
    const float* __restrict__ WK, const float* __restrict__ WV, bf16* __restrict__ Wm4)
{
    int d = blockIdx.x;
    int row = threadIdx.x >> 2, e0 = (threadIdx.x & 3) * 16;
    const float* pk = &WK[(long)row * 4096 + d * 64 + e0];
    const float* pv = &WV[(long)row * 4096 + d * 64 + e0];
    long bKh = (((long)(d * 4 + 0) * 64) + row) * 64 + e0;
    long bKl = (((long)(d * 4 + 1) * 64) + row) * 64 + e0;
    long bVh = (((long)(d * 4 + 2) * 64) + row) * 64 + e0;
    long bVl = (((long)(d * 4 + 3) * 64) + row) * 64 + e0;
    short8 h8, l8;
    split8(pk, h8, l8);     *(short8*)&Wm4[bKh] = h8;     *(short8*)&Wm4[bKl] = l8;
    split8(pk + 8, h8, l8); *(short8*)&Wm4[bKh + 8] = h8; *(short8*)&Wm4[bKl + 8] = l8;
    split8(pv, h8, l8);     *(short8*)&Wm4[bVh] = h8;     *(short8*)&Wm4[bVl] = l8;
    split8(pv + 8, h8, l8); *(short8*)&Wm4[bVh + 8] = h8; *(short8*)&Wm4[bVl + 8] = l8;
}

// ---------------------------------------------------------------------------
// Fused QKV GEMM from pre-split operands. blockIdx.x: 8 n-blocks x 3 projs.
// ---------------------------------------------------------------------------
__global__ __launch_bounds__(256) void qkv_kernel(
    const bf16* __restrict__ xh, const bf16* __restrict__ xl,
    const bf16* __restrict__ wqh, const bf16* __restrict__ wql,
    const bf16* __restrict__ wkh, const bf16* __restrict__ wkl,
    const bf16* __restrict__ wvh, const bf16* __restrict__ wvl,
    float* __restrict__ qkv)
{
    __shared__ bf16 Ah[8192], Al[8192], Bh[8192], Bl[8192];
    const int tid = threadIdx.x;
    const int lane = tid & 63, wid = tid >> 6;
    const int wr = wid >> 1, wc = wid & 1;
    const int proj = blockIdx.x >> 3;
    const int n0 = (blockIdx.x & 7) * 128;
    const int m0 = blockIdx.y * 128;
    const bf16* Bhp = proj == 0 ? wqh : (proj == 1 ? wkh : wvh);
    const bf16* Blp = proj == 0 ? wql : (proj == 1 ? wkl : wvl);
    float* C = qkv + (long)proj * 2097152;

    f32x4 acc[4][4] = {};
    for (int kt = 0; kt < 16; ++kt) {
        const int k0 = kt << 6;
#pragma unroll
        for (int i = 0; i < 4; ++i) {
            int cc = tid + i * 256;
            int row = cc >> 3, ch = cc & 7;
            *tchunk(Ah, row, ch) = *(const short8*)&xh[(long)(m0 + row) * 1024 + k0 + ch * 8];
            *tchunk(Al, row, ch) = *(const short8*)&xl[(long)(m0 + row) * 1024 + k0 + ch * 8];
            *tchunk(Bh, row, ch) = *(const short8*)&Bhp[(long)(n0 + row) * 1024 + k0 + ch * 8];
            *tchunk(Bl, row, ch) = *(const short8*)&Blp[(long)(n0 + row) * 1024 + k0 + ch * 8];
        }
        __syncthreads();
#pragma unroll
        for (int kk = 0; kk < 2; ++kk) {
            short8 afh[4], afl[4], bfh[4], bfl[4];
#pragma unroll
            for (int t = 0; t < 4; ++t) {
                int ra = wr * 64 + t * 16 + (lane & 15);
                int rb = wc * 64 + t * 16 + (lane & 15);
                int ch = kk * 4 + (lane >> 4);
                afh[t] = *tchunk(Ah, ra, ch);
                afl[t] = *tchunk(Al, ra, ch);
                bfh[t] = *tchunk(Bh, rb, ch);
                bfl[t] = *tchunk(Bl, rb, ch);
            }
#pragma unroll
            for (int tm = 0; tm < 4; ++tm)
#pragma unroll
                for (int tn = 0; tn < 4; ++tn) {
                    acc[tm][tn] = __builtin_amdgcn_mfma_f32_16x16x32_bf16(
                        afh[tm], bfh[tn], acc[tm][tn], 0, 0, 0);
                    acc[tm][tn] = __builtin_amdgcn_mfma_f32_16x16x32_bf16(
                        afh[tm], bfl[tn], acc[tm][tn], 0, 0, 0);
                    acc[tm][tn] = __builtin_amdgcn_mfma_f32_16x16x32_bf16(
                        afl[tm], bfh[tn], acc[tm][tn], 0, 0, 0);
                }
        }
        __syncthreads();
    }
#pragma unroll
    for (int tm = 0; tm < 4; ++tm)
#pragma unroll
        for (int tn = 0; tn < 4; ++tn)
#pragma unroll
            for (int r = 0; r < 4; ++r) {
                int row = m0 + wr * 64 + tm * 16 + (lane >> 4) * 4 + r;
                int col = n0 + wc * 64 + tn * 16 + (lane & 15);
                float v = acc[tm][tn][r];
                if (proj < 2) v = v > 0.f ? v + 1.f : __expf(v);
                C[(long)row * 1024 + col] = v;
            }
}

// ---------------------------------------------------------------------------
// setfeat v3 (G-formulation): per (b,h), for each d:
//   G_d[s,i] = sum_e v[s,e]*W[i,d*64+e]  (3-pass split MFMA, v-frags in reg)
//   out[s,i] += k[s,d] * G_d[s,i]        (fp32 VALU, kT broadcast from LDS)
// Then fp32 in-block cumsum -> tails; row 63 -> set features.
// ---------------------------------------------------------------------------
__global__ __launch_bounds__(256) void setfeat_kernel(
    const float* __restrict__ kbuf, const float* __restrict__ vbuf,
    const bf16* __restrict__ Wm4,
    const float* __restrict__ bkmap, const float* __restrict__ bvmap,
    float* __restrict__ Ktail, float* __restrict__ Vtail,
    float* __restrict__ Kset, float* __restrict__ Vset)
{
    __shared__ char smem[49152];
    bf16* Wt = reinterpret_cast<bf16*>(smem);              // 32KB: 4 parts x [64][64]
    float* kT = reinterpret_cast<float*>(smem + 32768);    // 16KB: kT[c][s]
    float(*WallK)[64] = reinterpret_cast<float(*)[64]>(smem);          // overlay
    float(*WallV)[64] = reinterpret_cast<float(*)[64]>(smem + 16384);  // overlay

    const int tid = threadIdx.x;
    const int lane = tid & 63, wid = tid >> 6;
    const int wr = wid >> 1, wc = wid & 1;
    const int b = blockIdx.x >> 4, h = blockIdx.x & 15;
    const long base_kv = ((long)b * 64) * C_DIM + h * HS;

    {   // stage kT[c][s] = k[s][c]
        int s = tid >> 2, cg = tid & 3;
        const float* src = &kbuf[base_kv + (long)s * C_DIM + cg * 16];
        float f[16];
#pragma unroll
        for (int j = 0; j < 4; ++j)
            *reinterpret_cast<float4*>(&f[j * 4]) = reinterpret_cast<const float4*>(src)[j];
#pragma unroll
        for (int j = 0; j < 16; ++j)
            kT[(cg * 16 + j) * 64 + s] = f[j];
    }
    // v fragments (loop-invariant A operand), exact hi/lo split in registers
    short8 vh[2][2], vl[2][2];
#pragma unroll
    for (int tm = 0; tm < 2; ++tm)
#pragma unroll
        for (int kk = 0; kk < 2; ++kk) {
            const float* vp = &vbuf[base_kv +
                (long)(wr * 32 + tm * 16 + (lane & 15)) * C_DIM + kk * 32 + (lane >> 4) * 8];
            split8(vp, vh[tm][kk], vl[tm][kk]);
        }
    f32x4 accK[2][2] = {}, accV[2][2] = {};
    __syncthreads();

    for (int d = 0; d < 64; ++d) {
        // stage W chunk: 2048 x 16B (4 parts x 64 rows x 8 chunks), swizzled
#pragma unroll
        for (int i = 0; i < 8; ++i) {
            int cc = tid + i * 256;
            int part = cc >> 9, row = (cc >> 3) & 63, ch = cc & 7;
            *tchunk(Wt + part * 4096, row, ch) =
                *(const short8*)&Wm4[(((long)(d * 4 + part) * 64) + row) * 64 + ch * 8];
        }
        __syncthreads();
        f32x4 GK[2][2] = {}, GV[2][2] = {};
#pragma unroll
        for (int kk = 0; kk < 2; ++kk) {
            short8 bkh[2], bkl[2], bvh[2], bvl[2];
#pragma unroll
            for (int t = 0; t < 2; ++t) {
                int rb = wc * 32 + t * 16 + (lane & 15);
                int ch = kk * 4 + (lane >> 4);
                bkh[t] = *tchunk(Wt,         rb, ch);
                bkl[t] = *tchunk(Wt + 4096,  rb, ch);
                bvh[t] = *tchunk(Wt + 8192,  rb, ch);
                bvl[t] = *tchunk(Wt + 12288, rb, ch);
            }
#pragma unroll
            for (int tm = 0; tm < 2; ++tm)
#pragma unroll
                for (int tn = 0; tn < 2; ++tn) {
                    GK[tm][tn] = __builtin_amdgcn_mfma_f32_16x16x32_bf16(
                        vh[tm][kk], bkh[tn], GK[tm][tn], 0, 0, 0);
                    GK[tm][tn] = __builtin_amdgcn_mfma_f32_16x16x32_bf16(
                        vh[tm][kk], bkl[tn], GK[tm][tn], 0, 0, 0);
                    GK[tm][tn] = __builtin_amdgcn_mfma_f32_16x16x32_bf16(
                        vl[tm][kk], bkh[tn], GK[tm][tn], 0, 0, 0);
                    GV[tm][tn] = __builtin_amdgcn_mfma_f32_16x16x32_bf16(
                        vh[tm][kk], bvh[tn], GV[tm][tn], 0, 0, 0);
                    GV[tm][tn] = __builtin_amdgcn_mfma_f32_16x16x32_bf16(
                        vh[tm][kk], bvl[tn], GV[tm][tn], 0, 0, 0);
                    GV[tm][tn] = __builtin_amdgcn_mfma_f32_16x16x32_bf16(
                        vl[tm][kk], bvh[tn], GV[tm][tn], 0, 0, 0);
                }
        }
        // combine: out[s,i] += k[s,d] * G_d[s,i]
#pragma unroll
        for (int tm = 0; tm < 2; ++tm) {
            f32x4 kv = *reinterpret_cast<const f32x4*>(
                &kT[d * 64 + wr * 32 + tm * 16 + (lane >> 4) * 4]);
#pragma unroll
            for (int tn = 0; tn < 2; ++tn)
#pragma unroll
                for (int r = 0; r < 4; ++r) {
                    accK[tm][tn][r] += kv[r] * GK[tm][tn][r];
                    accV[tm][tn][r] += kv[r] * GV[tm][tn][r];
                }
        }
        __syncthreads();
    }
#pragma unroll
    for (int tm = 0; tm < 2; ++tm)
#pragma unroll
        for (int tn = 0; tn < 2; ++tn)
#pragma unroll
            for (int r = 0; r < 4; ++r) {
                int row = wr * 32 + tm * 16 + (lane >> 4) * 4 + r;
                int col = wc * 32 + tn * 16 + (lane & 15);
                WallK[row][col] = accK[tm][tn][r];
                WallV[row][col] = accV[tm][tn][r];
            }
    __syncthreads();
    if (tid < 128) {
        int i = tid & 63;
        bool isV = tid >= 64;
        const float bi = isV ? bvmap[i] : bkmap[i];
        float run = 0.f;
        for (int s = 0; s < 64; ++s) {
            run += isV ? WallV[s][i] : WallK[s][i];
            float val = run + bi;
            long t = (long)b * 64 + s;
            if (isV) Vtail[t * C_DIM + h * HS + i] = val;
            else     Ktail[t * C_DIM + h * HS + i] = val;
            if (s == 63) {
                if (isV) Vset[(b * NHEAD + h) * HS + i] = val;
                else     Kset[(b * NHEAD + h) * HS + i] = val;
            }
        }
    }
}

// ---------------------------------------------------------------------------
// Attention: one wave per (t,h). Output written as bf16 hi/lo (pre-split).
// ---------------------------------------------------------------------------
__global__ __launch_bounds__(256) void attn_kernel(
    const float* __restrict__ qbuf, const float* __restrict__ Kset,
    const float* __restrict__ Vset, const float* __restrict__ Ktail,
    const float* __restrict__ Vtail, bf16* __restrict__ atth, bf16* __restrict__ attl)
{
    __shared__ float qsh[4][64];
    __shared__ float attsh[4][64];
    const int tid = threadIdx.x, lane = tid & 63, wid = tid >> 6;
    const int g = blockIdx.x * 4 + wid;
    const int t = g >> 4, h = g & 15;
    const int nb = t >> 6;
    const float scale = 0.125f;
    const long qoff = (long)t * C_DIM + h * HS;
    qsh[wid][lane] = qbuf[qoff + lane];
    __syncthreads();
    float logit = -INFINITY;
    if (lane < nb) {
        float s = 0.f;
        const float* Kp = &Kset[(lane * NHEAD + h) * HS];
        for (int d = 0; d < 64; ++d) s += qsh[wid][d] * Kp[d];
        logit = s * scale;
    } else if (lane == nb) {
        float s = 0.f;
        const float* Kp = &Ktail[qoff];
        for (int d = 0; d < 64; ++d) s += qsh[wid][d] * Kp[d];
        logit = s * scale;
    }
    float m = logit;
    for (int off = 32; off; off >>= 1) m = fmaxf(m, __shfl_xor(m, off, 64));
    float e = (lane <= nb) ? __expf(logit - m) : 0.f;
    float sum = e;
    for (int off = 32; off; off >>= 1) sum += __shfl_xor(sum, off, 64);
    attsh[wid][lane] = e / sum;
    __syncthreads();
    float out = 0.f;
    for (int s = 0; s < nb; ++s)
        out += attsh[wid][s] * Vset[(s * NHEAD + h) * HS + lane];
    out += attsh[wid][nb] * Vtail[qoff + lane];
    bf16 hb = __float2bfloat16(out);
    atth[qoff + lane] = hb;
    attl[qoff + lane] = __float2bfloat16(out - bf2f(hb));
}

// ---------------------------------------------------------------------------
// Final GEMM from pre-split operands: out = attout @ Wc^T + bc. 128x64 tiles.
// ---------------------------------------------------------------------------
__global__ __launch_bounds__(256) void gemm_final_kernel(
    const bf16* __restrict__ ah, const bf16* __restrict__ al,
    const bf16* __restrict__ bh, const bf16* __restrict__ bl,
    const float* __restrict__ bias, float* __restrict__ C)
{
    __shared__ bf16 Ah[8192], Al[8192], Bh[4096], Bl[4096];
    const int tid = threadIdx.x;
    const int lane = tid & 63, wid = tid >> 6;
    const int wr = wid >> 1, wc = wid & 1;
    const int m0 = blockIdx.y * 128, n0 = blockIdx.x * 64;

    f32x4 acc[4][2] = {};
    for (int kt = 0; kt < 16; ++kt) {
        const int k0 = kt << 6;
#pragma unroll
        for (int i = 0; i < 4; ++i) {
            int cc = tid + i * 256;
            int row = cc >> 3, ch = cc & 7;
            *tchunk(Ah, row, ch) = *(const short8*)&ah[(long)(m0 + row) * 1024 + k0 + ch * 8];
            *tchunk(Al, row, ch) = *(const short8*)&al[(long)(m0 + row) * 1024 + k0 + ch * 8];
        }
#pragma unroll
        for (int i = 0; i < 2; ++i) {
            int cc = tid + i * 256;
            int row = cc >> 3, ch = cc & 7;
            *tchunk(Bh, row, ch) = *(const short8*)&bh[(long)(n0 + row) * 1024 + k0 + ch * 8];
            *tchunk(Bl, row, ch) = *(const short8*)&bl[(long)(n0 + row) * 1024 + k0 + ch * 8];
        }
        __syncthreads();
#pragma unroll
        for (int kk = 0; kk < 2; ++kk) {
            short8 afh[4], afl[4], bfh[2], bfl[2];
#pragma unroll
            for (int t = 0; t < 4; ++t) {
                int ra = wr * 64 + t * 16 + (lane & 15);
                int ch = kk * 4 + (lane >> 4);
                afh[t] = *tchunk(Ah, ra, ch);
                afl[t] = *tchunk(Al, ra, ch);
            }
#pragma unroll
            for (int t = 0; t < 2; ++t) {
                int rb = wc * 32 + t * 16 + (lane & 15);
                int ch = kk * 4 + (lane >> 4);
                bfh[t] = *tchunk(Bh, rb, ch);
                bfl[t] = *tchunk(Bl, rb, ch);
            }
#pragma unroll
            for (int tm = 0; tm < 4; ++tm)
#pragma unroll
                for (int tn = 0; tn < 2; ++tn) {
                    acc[tm][tn] = __builtin_amdgcn_mfma_f32_16x16x32_bf16(
                        afh[tm], bfh[tn], acc[tm][tn], 0, 0, 0);
                    acc[tm][tn] = __builtin_amdgcn_mfma_f32_16x16x32_bf16(
                        afh[tm], bfl[tn], acc[tm][tn], 0, 0, 0);
                    acc[tm][tn] = __builtin_amdgcn_mfma_f32_16x16x32_bf16(
                        afl[tm], bfh[tn], acc[tm][tn], 0, 0, 0);
                }
        }
        __syncthreads();
    }
#pragma unroll
    for (int tm = 0; tm < 4; ++tm)
#pragma unroll
        for (int tn = 0; tn < 2; ++tn)
#pragma unroll
            for (int r = 0; r < 4; ++r) {
                int row = m0 + wr * 64 + tm * 16 + (lane >> 4) * 4 + r;
                int col = n0 + wc * 32 + tn * 16 + (lane & 15);
                C[(long)row * 1024 + col] = acc[tm][tn][r] + bias[col];
            }
}

// ---------------------------------------------------------------------------
extern "C" void kernel_launch(void* const* d_in, const int* in_sizes, int n_in,
                              void* d_out, int out_size, void* d_ws, size_t ws_size,
                              hipStream_t stream)
{
    const float* x     = (const float*)d_in[0];
    const float* Wq    = (const float*)d_in[1];
    const float* Wk    = (const float*)d_in[2];
    const float* Wv    = (const float*)d_in[3];
    const float* Wkmap = (const float*)d_in[4];
    const float* bkmap = (const float*)d_in[5];
    const float* Wvmap = (const float*)d_in[6];
    const float* bvmap = (const float*)d_in[7];
    const float* Wc    = (const float*)d_in[8];
    const float* bc    = (const float*)d_in[9];
    float* out = (float*)d_out;

    char* ws = (char*)d_ws;
    const long MB = 1l << 20;
    float* q   = (float*)(ws + 0 * MB);        // 8MB
    float* k   = (float*)(ws + 8 * MB);        // 8MB
    float* v   = (float*)(ws + 16 * MB);       // 8MB
    bf16* xh   = (bf16*)(ws + 24 * MB);        // 4MB (dead after qkv)
    bf16* xl   = (bf16*)(ws + 28 * MB);        // 4MB
    bf16* wqh  = (bf16*)(ws + 32 * MB);        // 2MB each (dead after qkv)
    bf16* wql  = (bf16*)(ws + 34 * MB);
    bf16* wkh  = (bf16*)(ws + 36 * MB);
    bf16* wkl  = (bf16*)(ws + 38 * MB);
    bf16* wvh  = (bf16*)(ws + 40 * MB);
    bf16* wvl  = (bf16*)(ws + 42 * MB);
    bf16* Wm4  = (bf16*)(ws + 44 * MB);        // 2MB (dead after setfeat)
    // post-qkv overlays:
    float* Ktail = (float*)(ws + 24 * MB);     // 8MB over xh/xl
    float* Vtail = (float*)(ws + 32 * MB);     // 8MB over wq/wk
    float* Kset  = (float*)(ws + 40 * MB);     // 128KB over wvh
    float* Vset  = (float*)(ws + 41 * MB);     // 128KB
    bf16* atth   = (bf16*)(ws + 8 * MB);       // 4MB over k (dead after setfeat)
    bf16* attl   = (bf16*)(ws + 12 * MB);      // 4MB
    bf16* wch    = (bf16*)(ws + 44 * MB);      // 2MB over Wm4 (written after setfeat)
    bf16* wcl    = (bf16*)(ws + 46 * MB);      // 2MB

    presplit_all_kernel<<<2560, 256, 0, stream>>>(x, Wq, Wk, Wv, xh, xl,
                                                  wqh, wql, wkh, wkl, wvh, wvl);
    presplit_wmap_kernel<<<64, 256, 0, stream>>>(Wkmap, Wvmap, Wm4);
    qkv_kernel<<<dim3(24, 16), 256, 0, stream>>>(xh, xl, wqh, wql, wkh, wkl,
                                                 wvh, wvl, q);
    setfeat_kernel<<<512, 256, 0, stream>>>(k, v, Wm4, bkmap, bvmap,
                                            Ktail, Vtail, Kset, Vset);
    presplit_wc_kernel<<<512, 256, 0, stream>>>(Wc, wch, wcl);
    attn_kernel<<<8192, 256, 0, stream>>>(q, Kset, Vset, Ktail, Vtail, atth, attl);
    gemm_final_kernel<<<dim3(16, 16), 256, 0, stream>>>(atth, attl, wch, wcl, bc, out);
}

// Round 7
// 292.207 us; speedup vs baseline: 1.7050x; 1.0402x over previous
//
#include <hip/hip_runtime.h>
#include <hip/hip_bf16.h>
#include <math.h>

typedef __hip_bfloat16 bf16;
typedef __attribute__((ext_vector_type(8))) short short8;
typedef __attribute__((ext_vector_type(4))) float f32x4;

#define C_DIM 1024
#define NHEAD 16
#define HS 64

__device__ __forceinline__ float bf2f(bf16 x) { return __bfloat162float(x); }

// Async global->LDS, 16B per lane. LDS dest is wave-uniform base + lane*16.
__device__ __forceinline__ void gl16(const void* g, void* l) {
    __builtin_amdgcn_global_load_lds(
        (const __attribute__((address_space(1))) unsigned int*)g,
        (__attribute__((address_space(3))) unsigned int*)l, 16, 0, 0);
}

// Split 8 consecutive floats into bf16 hi + bf16 lo (residual) short8s.
__device__ __forceinline__ void split8(const float* p, short8& h, short8& l) {
    float4 f0 = reinterpret_cast<const float4*>(p)[0];
    float4 f1 = reinterpret_cast<const float4*>(p)[1];
    float vals[8] = {f0.x, f0.y, f0.z, f0.w, f1.x, f1.y, f1.z, f1.w};
#pragma unroll
    for (int j = 0; j < 8; ++j) {
        bf16 hb = __float2bfloat16(vals[j]);
        float r = vals[j] - __bfloat162float(hb);
        h[j] = *reinterpret_cast<short*>(&hb);
        bf16 lb = __float2bfloat16(r);
        l[j] = *reinterpret_cast<short*>(&lb);
    }
}

// Swizzled-LDS fragment read: [rows][64] bf16 tile, 16B chunk slot = ch ^ (row&7).
__device__ __forceinline__ short8* tchunk(bf16* tile, int row, int ch) {
    return reinterpret_cast<short8*>(tile + row * 64 + (((ch) ^ (row & 7)) << 3));
}

// ---------------------------------------------------------------------------
// Pre-split x,Wq,Wk,Wv -> bf16 hi/lo, stored PRE-SWIZZLED (chunk bits [5:3] of
// the element index XOR'd with row&7, row = idx>>10) so global_load_lds can
// write linear LDS and tchunk reads still work. Grid 2560 x 256.
// ---------------------------------------------------------------------------
__global__ __launch_bounds__(256) void presplit_all_kernel(
    const float* __restrict__ x, const float* __restrict__ Wq,
    const float* __restrict__ Wk, const float* __restrict__ Wv,
    bf16* __restrict__ xh, bf16* __restrict__ xl,
    bf16* __restrict__ wqh, bf16* __restrict__ wql,
    bf16* __restrict__ wkh, bf16* __restrict__ wkl,
    bf16* __restrict__ wvh, bf16* __restrict__ wvl)
{
    int blk = blockIdx.x;
    const float* src; bf16 *dh, *dl; long off;
    if (blk < 1024)      { src = x;  dh = xh;  dl = xl;  off = (long)blk * 2048; }
    else if (blk < 1536) { src = Wq; dh = wqh; dl = wql; off = (long)(blk - 1024) * 2048; }
    else if (blk < 2048) { src = Wk; dh = wkh; dl = wkl; off = (long)(blk - 1536) * 2048; }
    else                 { src = Wv; dh = wvh; dl = wvl; off = (long)(blk - 2048) * 2048; }
    long p = off + threadIdx.x * 8;
    int j = (int)(((p >> 3) ^ (p >> 10)) & 7);
    long dp = (p & ~56l) | ((long)j << 3);
    short8 h8, l8;
    split8(&src[p], h8, l8);
    *reinterpret_cast<short8*>(&dh[dp]) = h8;
    *reinterpret_cast<short8*>(&dl[dp]) = l8;
}

// Pre-split Wc (pre-swizzled). Runs after setfeat (dest overlays Wm4).
__global__ __launch_bounds__(256) void presplit_wc_kernel(
    const float* __restrict__ Wc, bf16* __restrict__ wch, bf16* __restrict__ wcl)
{
    long p = (long)blockIdx.x * 2048 + threadIdx.x * 8;
    int j = (int)(((p >> 3) ^ (p >> 10)) & 7);
    long dp = (p & ~56l) | ((long)j << 3);
    short8 h8, l8;
    split8(&Wc[p], h8, l8);
    *reinterpret_cast<short8*>(&wch[dp]) = h8;
    *reinterpret_cast<short8*>(&wcl[dp]) = l8;
}

// ---------------------------------------------------------------------------
// Pre-split Wkmap/Wvmap -> Wm4[d][part][row][e] bf16 (part 0=Kh 1=Kl 2=Vh 3=Vl),
// stored pre-swizzled within each 64-elem row. Grid 64 (one block per d).
// ---------------------------------------------------------------------------
__global__ __launch_bounds__(256) void presplit_wmap_kernel(
    const float* __restrict__ WK, const float* __restrict__ WV, bf16* __restrict__ Wm4)
{
    int d = blockIdx.x;
    int row = threadIdx.x >> 2, e0 = (threadIdx.x & 3) * 16;
    int sw0 = (((e0 >> 3) + 0) ^ (row & 7)) & 7;
    int sw1 = (((e0 >> 3) + 1) ^ (row & 7)) & 7;
    const float* pk = &WK[(long)row * 4096 + d * 64 + e0];
    const float* pv = &WV[(long)row * 4096 + d * 64 + e0];
    long bKh = ((long)(d * 4 + 0) * 64 + row) * 64;
    long bKl = ((long)(d * 4 + 1) * 64 + row) * 64;
    long bVh = ((long)(d * 4 + 2) * 64 + row) * 64;
    long bVl = ((long)(d * 4 + 3) * 64 + row) * 64;
    short8 h8, l8;
    split8(pk, h8, l8);     *(short8*)&Wm4[bKh + sw0*8] = h8; *(short8*)&Wm4[bKl + sw0*8] = l8;
    split8(pk + 8, h8, l8); *(short8*)&Wm4[bKh + sw1*8] = h8; *(short8*)&Wm4[bKl + sw1*8] = l8;
    split8(pv, h8, l8);     *(short8*)&Wm4[bVh + sw0*8] = h8; *(short8*)&Wm4[bVl + sw0*8] = l8;
    split8(pv + 8, h8, l8); *(short8*)&Wm4[bVh + sw1*8] = h8; *(short8*)&Wm4[bVl + sw1*8] = l8;
}

// ---------------------------------------------------------------------------
// Fused QKV GEMM; staging via global_load_lds from pre-swizzled operands.
// ---------------------------------------------------------------------------
__global__ __launch_bounds__(256) void qkv_kernel(
    const bf16* __restrict__ xh, const bf16* __restrict__ xl,
    const bf16* __restrict__ wqh, const bf16* __restrict__ wql,
    const bf16* __restrict__ wkh, const bf16* __restrict__ wkl,
    const bf16* __restrict__ wvh, const bf16* __restrict__ wvl,
    float* __restrict__ qkv)
{
    __shared__ bf16 lds[32768];   // Ah 0 | Al 8192 | Bh 16384 | Bl 24576 (elems)
    const int tid = threadIdx.x;
    const int lane = tid & 63, wid = tid >> 6;
    const int wr = wid >> 1, wc = wid & 1;
    const int proj = blockIdx.x >> 3;
    const int n0 = (blockIdx.x & 7) * 128;
    const int m0 = blockIdx.y * 128;
    const bf16* Bhp = proj == 0 ? wqh : (proj == 1 ? wkh : wvh);
    const bf16* Blp = proj == 0 ? wql : (proj == 1 ? wkl : wvl);
    float* C = qkv + (long)proj * 2097152;
    char* lb = reinterpret_cast<char*>(lds);

    f32x4 acc[4][4] = {};
    for (int kt = 0; kt < 16; ++kt) {
        const int k0 = kt << 6;
#pragma unroll
        for (int i = 0; i < 4; ++i) {
            int cc = tid + i * 256;             // 1024 chunks per tile
            int row = cc >> 3, j = cc & 7;
            long soA = (long)(m0 + row) * 1024 + k0 + j * 8;
            long soB = (long)(n0 + row) * 1024 + k0 + j * 8;
            gl16(&xh[soA],  lb + cc * 16);
            gl16(&xl[soA],  lb + 16384 + cc * 16);
            gl16(&Bhp[soB], lb + 32768 + cc * 16);
            gl16(&Blp[soB], lb + 49152 + cc * 16);
        }
        __syncthreads();
#pragma unroll
        for (int kk = 0; kk < 2; ++kk) {
            short8 afh[4], afl[4], bfh[4], bfl[4];
#pragma unroll
            for (int t = 0; t < 4; ++t) {
                int ra = wr * 64 + t * 16 + (lane & 15);
                int rb = wc * 64 + t * 16 + (lane & 15);
                int ch = kk * 4 + (lane >> 4);
                afh[t] = *tchunk(lds, ra, ch);
                afl[t] = *tchunk(lds + 8192, ra, ch);
                bfh[t] = *tchunk(lds + 16384, rb, ch);
                bfl[t] = *tchunk(lds + 24576, rb, ch);
            }
#pragma unroll
            for (int tm = 0; tm < 4; ++tm)
#pragma unroll
                for (int tn = 0; tn < 4; ++tn) {
                    acc[tm][tn] = __builtin_amdgcn_mfma_f32_16x16x32_bf16(
                        afh[tm], bfh[tn], acc[tm][tn], 0, 0, 0);
                    acc[tm][tn] = __builtin_amdgcn_mfma_f32_16x16x32_bf16(
                        afh[tm], bfl[tn], acc[tm][tn], 0, 0, 0);
                    acc[tm][tn] = __builtin_amdgcn_mfma_f32_16x16x32_bf16(
                        afl[tm], bfh[tn], acc[tm][tn], 0, 0, 0);
                }
        }
        __syncthreads();
    }
#pragma unroll
    for (int tm = 0; tm < 4; ++tm)
#pragma unroll
        for (int tn = 0; tn < 4; ++tn)
#pragma unroll
            for (int r = 0; r < 4; ++r) {
                int row = m0 + wr * 64 + tm * 16 + (lane >> 4) * 4 + r;
                int col = n0 + wc * 64 + tn * 16 + (lane & 15);
                float v = acc[tm][tn][r];
                if (proj < 2) v = v > 0.f ? v + 1.f : __expf(v);
                C[(long)row * 1024 + col] = v;
            }
}

// ---------------------------------------------------------------------------
// setfeat v4: 256 blocks x 512 threads. Waves 0-3 -> pair 2*blk, waves 4-7 ->
// pair 2*blk+1; the W chunk for each d is staged ONCE (global_load_lds) and
// consumed by both. G_d = v @ W_d (3-pass split MFMA, v frags in registers),
// out += k[s,d]*G_d (fp32 VALU, kT per group). Then cumsum -> tails/sets.
// ---------------------------------------------------------------------------
__global__ __launch_bounds__(512) void setfeat_kernel(
    const float* __restrict__ kbuf, const float* __restrict__ vbuf,
    const bf16* __restrict__ Wm4,
    const float* __restrict__ bkmap, const float* __restrict__ bvmap,
    float* __restrict__ Ktail, float* __restrict__ Vtail,
    float* __restrict__ Kset, float* __restrict__ Vset)
{
    __shared__ char smem[65536];
    bf16* Wt = reinterpret_cast<bf16*>(smem);   // 32KB: 4 parts x [64][64] swz
    const int tid = threadIdx.x;
    const int grp = tid >> 8;                   // 0/1: which (b,h) pair
    const int tl = tid & 255;
    const int lane = tl & 63, wid = tl >> 6;
    const int wr = wid >> 1, wc = wid & 1;
    const int pairIdx = blockIdx.x * 2 + grp;
    const int b = pairIdx >> 4, h = pairIdx & 15;
    const long base_kv = ((long)b * 64) * C_DIM + h * HS;
    float* kT = reinterpret_cast<float*>(smem + 32768 + grp * 16384); // kT[c][s]

    {   // stage kT[c][s] = k[s][c] (per group)
        int s = tl >> 2, cg = tl & 3;
        const float* src = &kbuf[base_kv + (long)s * C_DIM + cg * 16];
        float f[16];
#pragma unroll
        for (int j = 0; j < 4; ++j)
            *reinterpret_cast<float4*>(&f[j * 4]) = reinterpret_cast<const float4*>(src)[j];
#pragma unroll
        for (int j = 0; j < 16; ++j)
            kT[(cg * 16 + j) * 64 + s] = f[j];
    }
    // v fragments (loop-invariant A operand), exact hi/lo split in registers
    short8 vh[2][2], vl[2][2];
#pragma unroll
    for (int tm = 0; tm < 2; ++tm)
#pragma unroll
        for (int kk = 0; kk < 2; ++kk) {
            const float* vp = &vbuf[base_kv +
                (long)(wr * 32 + tm * 16 + (lane & 15)) * C_DIM + kk * 32 + (lane >> 4) * 8];
            split8(vp, vh[tm][kk], vl[tm][kk]);
        }
    f32x4 accK[2][2] = {}, accV[2][2] = {};
    __syncthreads();

    for (int d = 0; d < 64; ++d) {
        // stage W chunk (2048 x 16B) linearly; source is pre-swizzled
#pragma unroll
        for (int i = 0; i < 4; ++i) {
            int cc = tid + i * 512;
            gl16(&Wm4[(long)d * 16384 + (long)cc * 8], smem + (long)cc * 16);
        }
        __syncthreads();
        f32x4 GK[2][2] = {}, GV[2][2] = {};
#pragma unroll
        for (int kk = 0; kk < 2; ++kk) {
            short8 bkh[2], bkl[2], bvh[2], bvl[2];
#pragma unroll
            for (int t = 0; t < 2; ++t) {
                int rb = wc * 32 + t * 16 + (lane & 15);
                int ch = kk * 4 + (lane >> 4);
                bkh[t] = *tchunk(Wt,         rb, ch);
                bkl[t] = *tchunk(Wt + 4096,  rb, ch);
                bvh[t] = *tchunk(Wt + 8192,  rb, ch);
                bvl[t] = *tchunk(Wt + 12288, rb, ch);
            }
#pragma unroll
            for (int tm = 0; tm < 2; ++tm)
#pragma unroll
                for (int tn = 0; tn < 2; ++tn) {
                    GK[tm][tn] = __builtin_amdgcn_mfma_f32_16x16x32_bf16(
                        vh[tm][kk], bkh[tn], GK[tm][tn], 0, 0, 0);
                    GK[tm][tn] = __builtin_amdgcn_mfma_f32_16x16x32_bf16(
                        vh[tm][kk], bkl[tn], GK[tm][tn], 0, 0, 0);
                    GK[tm][tn] = __builtin_amdgcn_mfma_f32_16x16x32_bf16(
                        vl[tm][kk], bkh[tn], GK[tm][tn], 0, 0, 0);
                    GV[tm][tn] = __builtin_amdgcn_mfma_f32_16x16x32_bf16(
                        vh[tm][kk], bvh[tn], GV[tm][tn], 0, 0, 0);
                    GV[tm][tn] = __builtin_amdgcn_mfma_f32_16x16x32_bf16(
                        vh[tm][kk], bvl[tn], GV[tm][tn], 0, 0, 0);
                    GV[tm][tn] = __builtin_amdgcn_mfma_f32_16x16x32_bf16(
                        vl[tm][kk], bvh[tn], GV[tm][tn], 0, 0, 0);
                }
        }
        // combine: out[s,i] += k[s,d] * G_d[s,i]
#pragma unroll
        for (int tm = 0; tm < 2; ++tm) {
            f32x4 kv = *reinterpret_cast<const f32x4*>(
                &kT[d * 64 + wr * 32 + tm * 16 + (lane >> 4) * 4]);
#pragma unroll
            for (int tn = 0; tn < 2; ++tn)
#pragma unroll
                for (int r = 0; r < 4; ++r) {
                    accK[tm][tn][r] += kv[r] * GK[tm][tn][r];
                    accV[tm][tn][r] += kv[r] * GV[tm][tn][r];
                }
        }
        __syncthreads();
    }
    // per-pair Wall overlays: pair0 [0,32KB), pair1 [32KB,64KB)
    float(*WallK)[64] = reinterpret_cast<float(*)[64]>(smem + grp * 32768);
    float(*WallV)[64] = reinterpret_cast<float(*)[64]>(smem + grp * 32768 + 16384);
#pragma unroll
    for (int tm = 0; tm < 2; ++tm)
#pragma unroll
        for (int tn = 0; tn < 2; ++tn)
#pragma unroll
            for (int r = 0; r < 4; ++r) {
                int row = wr * 32 + tm * 16 + (lane >> 4) * 4 + r;
                int col = wc * 32 + tn * 16 + (lane & 15);
                WallK[row][col] = accK[tm][tn][r];
                WallV[row][col] = accV[tm][tn][r];
            }
    __syncthreads();
    if (tl < 128) {
        int i = tl & 63;
        bool isV = tl >= 64;
        const float bi = isV ? bvmap[i] : bkmap[i];
        float run = 0.f;
        for (int s = 0; s < 64; ++s) {
            run += isV ? WallV[s][i] : WallK[s][i];
            float val = run + bi;
            long t = (long)b * 64 + s;
            if (isV) Vtail[t * C_DIM + h * HS + i] = val;
            else     Ktail[t * C_DIM + h * HS + i] = val;
            if (s == 63) {
                if (isV) Vset[(b * NHEAD + h) * HS + i] = val;
                else     Kset[(b * NHEAD + h) * HS + i] = val;
            }
        }
    }
}

// ---------------------------------------------------------------------------
// Attention: one wave per (t,h). Writes bf16 hi/lo PRE-SWIZZLED for gemm_final.
// ---------------------------------------------------------------------------
__global__ __launch_bounds__(256) void attn_kernel(
    const float* __restrict__ qbuf, const float* __restrict__ Kset,
    const float* __restrict__ Vset, const float* __restrict__ Ktail,
    const float* __restrict__ Vtail, bf16* __restrict__ atth, bf16* __restrict__ attl)
{
    __shared__ float qsh[4][64];
    __shared__ float attsh[4][64];
    const int tid = threadIdx.x, lane = tid & 63, wid = tid >> 6;
    const int g = blockIdx.x * 4 + wid;
    const int t = g >> 4, h = g & 15;
    const int nb = t >> 6;
    const float scale = 0.125f;
    const long qoff = (long)t * C_DIM + h * HS;
    qsh[wid][lane] = qbuf[qoff + lane];
    __syncthreads();
    float logit = -INFINITY;
    if (lane < nb) {
        float s = 0.f;
        const float* Kp = &Kset[(lane * NHEAD + h) * HS];
        for (int d = 0; d < 64; ++d) s += qsh[wid][d] * Kp[d];
        logit = s * scale;
    } else if (lane == nb) {
        float s = 0.f;
        const float* Kp = &Ktail[qoff];
        for (int d = 0; d < 64; ++d) s += qsh[wid][d] * Kp[d];
        logit = s * scale;
    }
    float m = logit;
    for (int off = 32; off; off >>= 1) m = fmaxf(m, __shfl_xor(m, off, 64));
    float e = (lane <= nb) ? __expf(logit - m) : 0.f;
    float sum = e;
    for (int off = 32; off; off >>= 1) sum += __shfl_xor(sum, off, 64);
    attsh[wid][lane] = e / sum;
    __syncthreads();
    float out = 0.f;
    for (int s = 0; s < nb; ++s)
        out += attsh[wid][s] * Vset[(s * NHEAD + h) * HS + lane];
    out += attsh[wid][nb] * Vtail[qoff + lane];
    bf16 hb = __float2bfloat16(out);
    int csw = (((lane >> 3) ^ (t & 7)) << 3) | (lane & 7);
    long po = (long)t * 1024 + h * 64 + csw;
    atth[po] = hb;
    attl[po] = __float2bfloat16(out - bf2f(hb));
}

// ---------------------------------------------------------------------------
// Final GEMM: out = attout @ Wc^T + bc. 128x64 tiles, global_load_lds staging.
// ---------------------------------------------------------------------------
__global__ __launch_bounds__(256) void gemm_final_kernel(
    const bf16* __restrict__ ah, const bf16* __restrict__ al,
    const bf16* __restrict__ bh, const bf16* __restrict__ bl,
    const float* __restrict__ bias, float* __restrict__ C)
{
    __shared__ bf16 lds[24576];   // Ah 0 | Al 8192 | Bh 16384 | Bl 20480 (elems)
    const int tid = threadIdx.x;
    const int lane = tid & 63, wid = tid >> 6;
    const int wr = wid >> 1, wc = wid & 1;
    const int m0 = blockIdx.y * 128, n0 = blockIdx.x * 64;
    char* lb = reinterpret_cast<char*>(lds);

    f32x4 acc[4][2] = {};
    for (int kt = 0; kt < 16; ++kt) {
        const int k0 = kt << 6;
#pragma unroll
        for (int i = 0; i < 4; ++i) {
            int cc = tid + i * 256;
            int row = cc >> 3, j = cc & 7;
            long so = (long)(m0 + row) * 1024 + k0 + j * 8;
            gl16(&ah[so], lb + cc * 16);
            gl16(&al[so], lb + 16384 + cc * 16);
        }
#pragma unroll
        for (int i = 0; i < 2; ++i) {
            int cc = tid + i * 256;
            int row = cc >> 3, j = cc & 7;
            long so = (long)(n0 + row) * 1024 + k0 + j * 8;
            gl16(&bh[so], lb + 32768 + cc * 16);
            gl16(&bl[so], lb + 40960 + cc * 16);
        }
        __syncthreads();
#pragma unroll
        for (int kk = 0; kk < 2; ++kk) {
            short8 afh[4], afl[4], bfh[2], bfl[2];
#pragma unroll
            for (int t = 0; t < 4; ++t) {
                int ra = wr * 64 + t * 16 + (lane & 15);
                int ch = kk * 4 + (lane >> 4);
                afh[t] = *tchunk(lds, ra, ch);
                afl[t] = *tchunk(lds + 8192, ra, ch);
            }
#pragma unroll
            for (int t = 0; t < 2; ++t) {
                int rb = wc * 32 + t * 16 + (lane & 15);
                int ch = kk * 4 + (lane >> 4);
                bfh[t] = *tchunk(lds + 16384, rb, ch);
                bfl[t] = *tchunk(lds + 20480, rb, ch);
            }
#pragma unroll
            for (int tm = 0; tm < 4; ++tm)
#pragma unroll
                for (int tn = 0; tn < 2; ++tn) {
                    acc[tm][tn] = __builtin_amdgcn_mfma_f32_16x16x32_bf16(
                        afh[tm], bfh[tn], acc[tm][tn], 0, 0, 0);
                    acc[tm][tn] = __builtin_amdgcn_mfma_f32_16x16x32_bf16(
                        afh[tm], bfl[tn], acc[tm][tn], 0, 0, 0);
                    acc[tm][tn] = __builtin_amdgcn_mfma_f32_16x16x32_bf16(
                        afl[tm], bfh[tn], acc[tm][tn], 0, 0, 0);
                }
        }
        __syncthreads();
    }
#pragma unroll
    for (int tm = 0; tm < 4; ++tm)
#pragma unroll
        for (int tn = 0; tn < 2; ++tn)
#pragma unroll
            for (int r = 0; r < 4; ++r) {
                int row = m0 + wr * 64 + tm * 16 + (lane >> 4) * 4 + r;
                int col = n0 + wc * 32 + tn * 16 + (lane & 15);
                C[(long)row * 1024 + col] = acc[tm][tn][r] + bias[col];
            }
}

// ---------------------------------------------------------------------------
extern "C" void kernel_launch(void* const* d_in, const int* in_sizes, int n_in,
                              void* d_out, int out_size, void* d_ws, size_t ws_size,
                              hipStream_t stream)
{
    const float* x     = (const float*)d_in[0];
    const float* Wq    = (const float*)d_in[1];
    const float* Wk    = (const float*)d_in[2];
    const float* Wv    = (const float*)d_in[3];
    const float* Wkmap = (const float*)d_in[4];
    const float* bkmap = (const float*)d_in[5];
    const float* Wvmap = (const float*)d_in[6];
    const float* bvmap = (const float*)d_in[7];
    const float* Wc    = (const float*)d_in[8];
    const float* bc    = (const float*)d_in[9];
    float* out = (float*)d_out;

    char* ws = (char*)d_ws;
    const long MB = 1l << 20;
    float* q   = (float*)(ws + 0 * MB);        // 8MB
    float* k   = (float*)(ws + 8 * MB);        // 8MB
    float* v   = (float*)(ws + 16 * MB);       // 8MB
    bf16* xh   = (bf16*)(ws + 24 * MB);        // 4MB (dead after qkv)
    bf16* xl   = (bf16*)(ws + 28 * MB);        // 4MB
    bf16* wqh  = (bf16*)(ws + 32 * MB);        // 2MB each (dead after qkv)
    bf16* wql  = (bf16*)(ws + 34 * MB);
    bf16* wkh  = (bf16*)(ws + 36 * MB);
    bf16* wkl  = (bf16*)(ws + 38 * MB);
    bf16* wvh  = (bf16*)(ws + 40 * MB);
    bf16* wvl  = (bf16*)(ws + 42 * MB);
    bf16* Wm4  = (bf16*)(ws + 44 * MB);        // 2MB (dead after setfeat)
    // post-qkv overlays:
    float* Ktail = (float*)(ws + 24 * MB);     // 8MB over xh/xl
    float* Vtail = (float*)(ws + 32 * MB);     // 8MB over wq/wk
    float* Kset  = (float*)(ws + 40 * MB);     // 128KB over wvh
    float* Vset  = (float*)(ws + 41 * MB);     // 128KB
    bf16* atth   = (bf16*)(ws + 8 * MB);       // 4MB over k (dead after setfeat)
    bf16* attl   = (bf16*)(ws + 12 * MB);      // 4MB
    bf16* wch    = (bf16*)(ws + 44 * MB);      // 2MB over Wm4 (written after setfeat)
    bf16* wcl    = (bf16*)(ws + 46 * MB);      // 2MB

    presplit_all_kernel<<<2560, 256, 0, stream>>>(x, Wq, Wk, Wv, xh, xl,
                                                  wqh, wql, wkh, wkl, wvh, wvl);
    presplit_wmap_kernel<<<64, 256, 0, stream>>>(Wkmap, Wvmap, Wm4);
    qkv_kernel<<<dim3(24, 16), 256, 0, stream>>>(xh, xl, wqh, wql, wkh, wkl,
                                                 wvh, wvl, q);
    setfeat_kernel<<<256, 512, 0, stream>>>(k, v, Wm4, bkmap, bvmap,
                                            Ktail, Vtail, Kset, Vset);
    presplit_wc_kernel<<<512, 256, 0, stream>>>(Wc, wch, wcl);
    attn_kernel<<<8192, 256, 0, stream>>>(q, Kset, Vset, Ktail, Vtail, atth, attl);
    gemm_final_kernel<<<dim3(16, 16), 256, 0, stream>>>(atth, attl, wch, wcl, bc, out);
}

// Round 8
// 266.239 us; speedup vs baseline: 1.8713x; 1.0975x over previous
//
#include <hip/hip_runtime.h>
#include <hip/hip_bf16.h>
#include <math.h>

typedef __hip_bfloat16 bf16;
typedef __attribute__((ext_vector_type(8))) short short8;
typedef __attribute__((ext_vector_type(4))) float f32x4;

#define C_DIM 1024
#define NHEAD 16
#define HS 64

__device__ __forceinline__ float bf2f(bf16 x) { return __bfloat162float(x); }

// Async global->LDS, 16B per lane. LDS dest is wave-uniform base + lane*16.
__device__ __forceinline__ void gl16(const void* g, void* l) {
    __builtin_amdgcn_global_load_lds(
        (const __attribute__((address_space(1))) unsigned int*)g,
        (__attribute__((address_space(3))) unsigned int*)l, 16, 0, 0);
}

// Split 8 consecutive floats into bf16 hi + bf16 lo (residual) short8s.
__device__ __forceinline__ void split8(const float* p, short8& h, short8& l) {
    float4 f0 = reinterpret_cast<const float4*>(p)[0];
    float4 f1 = reinterpret_cast<const float4*>(p)[1];
    float vals[8] = {f0.x, f0.y, f0.z, f0.w, f1.x, f1.y, f1.z, f1.w};
#pragma unroll
    for (int j = 0; j < 8; ++j) {
        bf16 hb = __float2bfloat16(vals[j]);
        float r = vals[j] - __bfloat162float(hb);
        h[j] = *reinterpret_cast<short*>(&hb);
        bf16 lb = __float2bfloat16(r);
        l[j] = *reinterpret_cast<short*>(&lb);
    }
}

// Swizzled-LDS fragment read: [rows][64] bf16 tile, 16B chunk slot = ch ^ (row&7).
__device__ __forceinline__ short8* tchunk(bf16* tile, int row, int ch) {
    return reinterpret_cast<short8*>(tile + row * 64 + (((ch) ^ (row & 7)) << 3));
}

// ---------------------------------------------------------------------------
// Pre-split x,Wq,Wk,Wv -> bf16 hi/lo, stored PRE-SWIZZLED (chunk bits [5:3] of
// the element index XOR'd with row&7, row = idx>>10). Grid 2560 x 256.
// ---------------------------------------------------------------------------
__global__ __launch_bounds__(256) void presplit_all_kernel(
    const float* __restrict__ x, const float* __restrict__ Wq,
    const float* __restrict__ Wk, const float* __restrict__ Wv,
    bf16* __restrict__ xh, bf16* __restrict__ xl,
    bf16* __restrict__ wqh, bf16* __restrict__ wql,
    bf16* __restrict__ wkh, bf16* __restrict__ wkl,
    bf16* __restrict__ wvh, bf16* __restrict__ wvl)
{
    int blk = blockIdx.x;
    const float* src; bf16 *dh, *dl; long off;
    if (blk < 1024)      { src = x;  dh = xh;  dl = xl;  off = (long)blk * 2048; }
    else if (blk < 1536) { src = Wq; dh = wqh; dl = wql; off = (long)(blk - 1024) * 2048; }
    else if (blk < 2048) { src = Wk; dh = wkh; dl = wkl; off = (long)(blk - 1536) * 2048; }
    else                 { src = Wv; dh = wvh; dl = wvl; off = (long)(blk - 2048) * 2048; }
    long p = off + threadIdx.x * 8;
    int j = (int)(((p >> 3) ^ (p >> 10)) & 7);
    long dp = (p & ~56l) | ((long)j << 3);
    short8 h8, l8;
    split8(&src[p], h8, l8);
    *reinterpret_cast<short8*>(&dh[dp]) = h8;
    *reinterpret_cast<short8*>(&dl[dp]) = l8;
}

// Pre-split Wc (pre-swizzled). Runs after setfeat (dest overlays Wm4).
__global__ __launch_bounds__(256) void presplit_wc_kernel(
    const float* __restrict__ Wc, bf16* __restrict__ wch, bf16* __restrict__ wcl)
{
    long p = (long)blockIdx.x * 2048 + threadIdx.x * 8;
    int j = (int)(((p >> 3) ^ (p >> 10)) & 7);
    long dp = (p & ~56l) | ((long)j << 3);
    short8 h8, l8;
    split8(&Wc[p], h8, l8);
    *reinterpret_cast<short8*>(&wch[dp]) = h8;
    *reinterpret_cast<short8*>(&wcl[dp]) = l8;
}

// ---------------------------------------------------------------------------
// Pre-split Wkmap/Wvmap -> Wm4[d][part][row][e] bf16 (part 0=Kh 1=Kl 2=Vh 3=Vl),
// pre-swizzled within each 64-elem row. Grid 64 (one block per d).
// ---------------------------------------------------------------------------
__global__ __launch_bounds__(256) void presplit_wmap_kernel(
    const float* __restrict__ WK, const float* __restrict__ WV, bf16* __restrict__ Wm4)
{
    int d = blockIdx.x;
    int row = threadIdx.x >> 2, e0 = (threadIdx.x & 3) * 16;
    int sw0 = (((e0 >> 3) + 0) ^ (row & 7)) & 7;
    int sw1 = (((e0 >> 3) + 1) ^ (row & 7)) & 7;
    const float* pk = &WK[(long)row * 4096 + d * 64 + e0];
    const float* pv = &WV[(long)row * 4096 + d * 64 + e0];
    long bKh = ((long)(d * 4 + 0) * 64 + row) * 64;
    long bKl = ((long)(d * 4 + 1) * 64 + row) * 64;
    long bVh = ((long)(d * 4 + 2) * 64 + row) * 64;
    long bVl = ((long)(d * 4 + 3) * 64 + row) * 64;
    short8 h8, l8;
    split8(pk, h8, l8);     *(short8*)&Wm4[bKh + sw0*8] = h8; *(short8*)&Wm4[bKl + sw0*8] = l8;
    split8(pk + 8, h8, l8); *(short8*)&Wm4[bKh + sw1*8] = h8; *(short8*)&Wm4[bKl + sw1*8] = l8;
    split8(pv, h8, l8);     *(short8*)&Wm4[bVh + sw0*8] = h8; *(short8*)&Wm4[bVl + sw0*8] = l8;
    split8(pv + 8, h8, l8); *(short8*)&Wm4[bVh + sw1*8] = h8; *(short8*)&Wm4[bVl + sw1*8] = l8;
}

// ---------------------------------------------------------------------------
// Fused QKV GEMM; staging via global_load_lds from pre-swizzled operands.
// ---------------------------------------------------------------------------
__global__ __launch_bounds__(256) void qkv_kernel(
    const bf16* __restrict__ xh, const bf16* __restrict__ xl,
    const bf16* __restrict__ wqh, const bf16* __restrict__ wql,
    const bf16* __restrict__ wkh, const bf16* __restrict__ wkl,
    const bf16* __restrict__ wvh, const bf16* __restrict__ wvl,
    float* __restrict__ qkv)
{
    __shared__ bf16 lds[32768];   // Ah 0 | Al 8192 | Bh 16384 | Bl 24576 (elems)
    const int tid = threadIdx.x;
    const int lane = tid & 63, wid = tid >> 6;
    const int wr = wid >> 1, wc = wid & 1;
    const int proj = blockIdx.x >> 3;
    const int n0 = (blockIdx.x & 7) * 128;
    const int m0 = blockIdx.y * 128;
    const bf16* Bhp = proj == 0 ? wqh : (proj == 1 ? wkh : wvh);
    const bf16* Blp = proj == 0 ? wql : (proj == 1 ? wkl : wvl);
    float* C = qkv + (long)proj * 2097152;
    char* lb = reinterpret_cast<char*>(lds);

    f32x4 acc[4][4] = {};
    for (int kt = 0; kt < 16; ++kt) {
        const int k0 = kt << 6;
#pragma unroll
        for (int i = 0; i < 4; ++i) {
            int cc = tid + i * 256;             // 1024 chunks per tile
            int row = cc >> 3, j = cc & 7;
            long soA = (long)(m0 + row) * 1024 + k0 + j * 8;
            long soB = (long)(n0 + row) * 1024 + k0 + j * 8;
            gl16(&xh[soA],  lb + cc * 16);
            gl16(&xl[soA],  lb + 16384 + cc * 16);
            gl16(&Bhp[soB], lb + 32768 + cc * 16);
            gl16(&Blp[soB], lb + 49152 + cc * 16);
        }
        __syncthreads();
#pragma unroll
        for (int kk = 0; kk < 2; ++kk) {
            short8 afh[4], afl[4], bfh[4], bfl[4];
#pragma unroll
            for (int t = 0; t < 4; ++t) {
                int ra = wr * 64 + t * 16 + (lane & 15);
                int rb = wc * 64 + t * 16 + (lane & 15);
                int ch = kk * 4 + (lane >> 4);
                afh[t] = *tchunk(lds, ra, ch);
                afl[t] = *tchunk(lds + 8192, ra, ch);
                bfh[t] = *tchunk(lds + 16384, rb, ch);
                bfl[t] = *tchunk(lds + 24576, rb, ch);
            }
#pragma unroll
            for (int tm = 0; tm < 4; ++tm)
#pragma unroll
                for (int tn = 0; tn < 4; ++tn) {
                    acc[tm][tn] = __builtin_amdgcn_mfma_f32_16x16x32_bf16(
                        afh[tm], bfh[tn], acc[tm][tn], 0, 0, 0);
                    acc[tm][tn] = __builtin_amdgcn_mfma_f32_16x16x32_bf16(
                        afh[tm], bfl[tn], acc[tm][tn], 0, 0, 0);
                    acc[tm][tn] = __builtin_amdgcn_mfma_f32_16x16x32_bf16(
                        afl[tm], bfh[tn], acc[tm][tn], 0, 0, 0);
                }
        }
        __syncthreads();
    }
#pragma unroll
    for (int tm = 0; tm < 4; ++tm)
#pragma unroll
        for (int tn = 0; tn < 4; ++tn)
#pragma unroll
            for (int r = 0; r < 4; ++r) {
                int row = m0 + wr * 64 + tm * 16 + (lane >> 4) * 4 + r;
                int col = n0 + wc * 64 + tn * 16 + (lane & 15);
                float v = acc[tm][tn][r];
                if (proj < 2) v = v > 0.f ? v + 1.f : __expf(v);
                C[(long)row * 1024 + col] = v;
            }
}

// ---------------------------------------------------------------------------
// setfeat v5: 256 blocks x 512 threads, 2 (b,h) pairs/block sharing W staging.
// T3-lite double-buffer: issue STAGE(d+1) before compute(d); ONE barrier/iter
// (its implicit vmcnt(0) is the drain). W dbuf 2x32KB + kT 2x16KB = 96KB LDS.
// ---------------------------------------------------------------------------
__global__ __launch_bounds__(512) void setfeat_kernel(
    const float* __restrict__ kbuf, const float* __restrict__ vbuf,
    const bf16* __restrict__ Wm4,
    const float* __restrict__ bkmap, const float* __restrict__ bvmap,
    float* __restrict__ Ktail, float* __restrict__ Vtail,
    float* __restrict__ KsetT, float* __restrict__ Vset)
{
    __shared__ char smem[98304];
    bf16* W0 = reinterpret_cast<bf16*>(smem);            // 32KB
    bf16* W1 = reinterpret_cast<bf16*>(smem + 32768);    // 32KB
    const int tid = threadIdx.x;
    const int grp = tid >> 8;                   // 0/1: which (b,h) pair
    const int tl = tid & 255;
    const int lane = tl & 63, wid = tl >> 6;
    const int wr = wid >> 1, wc = wid & 1;
    const int pairIdx = blockIdx.x * 2 + grp;
    const int b = pairIdx >> 4, h = pairIdx & 15;
    const long base_kv = ((long)b * 64) * C_DIM + h * HS;
    float* kT = reinterpret_cast<float*>(smem + 65536 + grp * 16384); // kT[c][s]

    {   // stage kT[c][s] = k[s][c] (per group)
        int s = tl >> 2, cg = tl & 3;
        const float* src = &kbuf[base_kv + (long)s * C_DIM + cg * 16];
        float f[16];
#pragma unroll
        for (int j = 0; j < 4; ++j)
            *reinterpret_cast<float4*>(&f[j * 4]) = reinterpret_cast<const float4*>(src)[j];
#pragma unroll
        for (int j = 0; j < 16; ++j)
            kT[(cg * 16 + j) * 64 + s] = f[j];
    }
    // v fragments (loop-invariant A operand), exact hi/lo split in registers
    short8 vh[2][2], vl[2][2];
#pragma unroll
    for (int tm = 0; tm < 2; ++tm)
#pragma unroll
        for (int kk = 0; kk < 2; ++kk) {
            const float* vp = &vbuf[base_kv +
                (long)(wr * 32 + tm * 16 + (lane & 15)) * C_DIM + kk * 32 + (lane >> 4) * 8];
            split8(vp, vh[tm][kk], vl[tm][kk]);
        }
    // prologue: stage W chunk for d=0 into W0
#pragma unroll
    for (int i = 0; i < 4; ++i) {
        int cc = tid + i * 512;
        gl16(&Wm4[(long)cc * 8], smem + (long)cc * 16);
    }
    f32x4 accK[2][2] = {}, accV[2][2] = {};
    __syncthreads();

    for (int d = 0; d < 64; ++d) {
        bf16* Wcur = (d & 1) ? W1 : W0;
        char* Wnxt = (d & 1) ? smem : smem + 32768;
        if (d < 63) {
#pragma unroll
            for (int i = 0; i < 4; ++i) {
                int cc = tid + i * 512;
                gl16(&Wm4[(long)(d + 1) * 16384 + (long)cc * 8], Wnxt + (long)cc * 16);
            }
        }
        f32x4 GK[2][2] = {}, GV[2][2] = {};
#pragma unroll
        for (int kk = 0; kk < 2; ++kk) {
            short8 bkh[2], bkl[2], bvh[2], bvl[2];
#pragma unroll
            for (int t = 0; t < 2; ++t) {
                int rb = wc * 32 + t * 16 + (lane & 15);
                int ch = kk * 4 + (lane >> 4);
                bkh[t] = *tchunk(Wcur,         rb, ch);
                bkl[t] = *tchunk(Wcur + 4096,  rb, ch);
                bvh[t] = *tchunk(Wcur + 8192,  rb, ch);
                bvl[t] = *tchunk(Wcur + 12288, rb, ch);
            }
#pragma unroll
            for (int tm = 0; tm < 2; ++tm)
#pragma unroll
                for (int tn = 0; tn < 2; ++tn) {
                    GK[tm][tn] = __builtin_amdgcn_mfma_f32_16x16x32_bf16(
                        vh[tm][kk], bkh[tn], GK[tm][tn], 0, 0, 0);
                    GK[tm][tn] = __builtin_amdgcn_mfma_f32_16x16x32_bf16(
                        vh[tm][kk], bkl[tn], GK[tm][tn], 0, 0, 0);
                    GK[tm][tn] = __builtin_amdgcn_mfma_f32_16x16x32_bf16(
                        vl[tm][kk], bkh[tn], GK[tm][tn], 0, 0, 0);
                    GV[tm][tn] = __builtin_amdgcn_mfma_f32_16x16x32_bf16(
                        vh[tm][kk], bvh[tn], GV[tm][tn], 0, 0, 0);
                    GV[tm][tn] = __builtin_amdgcn_mfma_f32_16x16x32_bf16(
                        vh[tm][kk], bvl[tn], GV[tm][tn], 0, 0, 0);
                    GV[tm][tn] = __builtin_amdgcn_mfma_f32_16x16x32_bf16(
                        vl[tm][kk], bvh[tn], GV[tm][tn], 0, 0, 0);
                }
        }
        // combine: out[s,i] += k[s,d] * G_d[s,i]
#pragma unroll
        for (int tm = 0; tm < 2; ++tm) {
            f32x4 kv = *reinterpret_cast<const f32x4*>(
                &kT[d * 64 + wr * 32 + tm * 16 + (lane >> 4) * 4]);
#pragma unroll
            for (int tn = 0; tn < 2; ++tn)
#pragma unroll
                for (int r = 0; r < 4; ++r) {
                    accK[tm][tn][r] += kv[r] * GK[tm][tn][r];
                    accV[tm][tn][r] += kv[r] * GV[tm][tn][r];
                }
        }
        __syncthreads();   // drains stage(d+1) (auto vmcnt0) + protects dbuf swap
    }
    // per-pair Wall overlays: pair0 [0,32KB), pair1 [32KB,64KB)
    float(*WallK)[64] = reinterpret_cast<float(*)[64]>(smem + grp * 32768);
    float(*WallV)[64] = reinterpret_cast<float(*)[64]>(smem + grp * 32768 + 16384);
#pragma unroll
    for (int tm = 0; tm < 2; ++tm)
#pragma unroll
        for (int tn = 0; tn < 2; ++tn)
#pragma unroll
            for (int r = 0; r < 4; ++r) {
                int row = wr * 32 + tm * 16 + (lane >> 4) * 4 + r;
                int col = wc * 32 + tn * 16 + (lane & 15);
                WallK[row][col] = accK[tm][tn][r];
                WallV[row][col] = accV[tm][tn][r];
            }
    __syncthreads();
    if (tl < 128) {
        int i = tl & 63;
        bool isV = tl >= 64;
        const float bi = isV ? bvmap[i] : bkmap[i];
        float run = 0.f;
        for (int s = 0; s < 64; ++s) {
            run += isV ? WallV[s][i] : WallK[s][i];
            float val = run + bi;
            long t = (long)b * 64 + s;
            if (isV) Vtail[t * C_DIM + h * HS + i] = val;
            else     Ktail[t * C_DIM + h * HS + i] = val;
            if (s == 63) {
                if (isV) Vset[(b * NHEAD + h) * HS + i] = val;
                else     KsetT[h * 2048 + i * 32 + b] = val;  // transposed [h][d][b]
            }
        }
    }
}

// ---------------------------------------------------------------------------
// Attention: one wave per (t,h). Tail logit wave-parallel; set-dot reads
// KsetT[h][d][s] (lane s consecutive -> coalesced). Writes pre-swizzled hi/lo.
// ---------------------------------------------------------------------------
__global__ __launch_bounds__(256) void attn_kernel(
    const float* __restrict__ qbuf, const float* __restrict__ KsetT,
    const float* __restrict__ Vset, const float* __restrict__ Ktail,
    const float* __restrict__ Vtail, bf16* __restrict__ atth, bf16* __restrict__ attl)
{
    __shared__ float qsh[4][64];
    __shared__ float attsh[4][64];
    const int tid = threadIdx.x, lane = tid & 63, wid = tid >> 6;
    const int g = blockIdx.x * 4 + wid;
    const int t = g >> 4, h = g & 15;
    const int nb = t >> 6;
    const float scale = 0.125f;
    const long qoff = (long)t * C_DIM + h * HS;
    float qv = qbuf[qoff + lane];
    qsh[wid][lane] = qv;
    // tail logit: wave-parallel dot + reduce (all lanes get sum)
    float tp = qv * Ktail[qoff + lane];
    for (int off = 32; off; off >>= 1) tp += __shfl_xor(tp, off, 64);
    __syncthreads();
    float logit = -INFINITY;
    if (lane < nb) {
        float s = 0.f;
        const float* Kp = &KsetT[h * 2048 + lane];     // + d*32
        for (int d = 0; d < 64; ++d) s += qsh[wid][d] * Kp[d * 32];
        logit = s * scale;
    } else if (lane == nb) {
        logit = tp * scale;
    }
    float m = logit;
    for (int off = 32; off; off >>= 1) m = fmaxf(m, __shfl_xor(m, off, 64));
    float e = (lane <= nb) ? __expf(logit - m) : 0.f;
    float sum = e;
    for (int off = 32; off; off >>= 1) sum += __shfl_xor(sum, off, 64);
    attsh[wid][lane] = e / sum;
    __syncthreads();
    float out = 0.f;
    for (int s = 0; s < nb; ++s)
        out += attsh[wid][s] * Vset[(s * NHEAD + h) * HS + lane];
    out += attsh[wid][nb] * Vtail[qoff + lane];
    bf16 hb = __float2bfloat16(out);
    int csw = (((lane >> 3) ^ (t & 7)) << 3) | (lane & 7);
    long po = (long)t * 1024 + h * 64 + csw;
    atth[po] = hb;
    attl[po] = __float2bfloat16(out - bf2f(hb));
}

// ---------------------------------------------------------------------------
// Final GEMM: out = attout @ Wc^T + bc. 128x64 tiles, global_load_lds staging.
// ---------------------------------------------------------------------------
__global__ __launch_bounds__(256) void gemm_final_kernel(
    const bf16* __restrict__ ah, const bf16* __restrict__ al,
    const bf16* __restrict__ bh, const bf16* __restrict__ bl,
    const float* __restrict__ bias, float* __restrict__ C)
{
    __shared__ bf16 lds[24576];   // Ah 0 | Al 8192 | Bh 16384 | Bl 20480 (elems)
    const int tid = threadIdx.x;
    const int lane = tid & 63, wid = tid >> 6;
    const int wr = wid >> 1, wc = wid & 1;
    const int m0 = blockIdx.y * 128, n0 = blockIdx.x * 64;
    char* lb = reinterpret_cast<char*>(lds);

    f32x4 acc[4][2] = {};
    for (int kt = 0; kt < 16; ++kt) {
        const int k0 = kt << 6;
#pragma unroll
        for (int i = 0; i < 4; ++i) {
            int cc = tid + i * 256;
            int row = cc >> 3, j = cc & 7;
            long so = (long)(m0 + row) * 1024 + k0 + j * 8;
            gl16(&ah[so], lb + cc * 16);
            gl16(&al[so], lb + 16384 + cc * 16);
        }
#pragma unroll
        for (int i = 0; i < 2; ++i) {
            int cc = tid + i * 256;
            int row = cc >> 3, j = cc & 7;
            long so = (long)(n0 + row) * 1024 + k0 + j * 8;
            gl16(&bh[so], lb + 32768 + cc * 16);
            gl16(&bl[so], lb + 40960 + cc * 16);
        }
        __syncthreads();
#pragma unroll
        for (int kk = 0; kk < 2; ++kk) {
            short8 afh[4], afl[4], bfh[2], bfl[2];
#pragma unroll
            for (int t = 0; t < 4; ++t) {
                int ra = wr * 64 + t * 16 + (lane & 15);
                int ch = kk * 4 + (lane >> 4);
                afh[t] = *tchunk(lds, ra, ch);
                afl[t] = *tchunk(lds + 8192, ra, ch);
            }
#pragma unroll
            for (int t = 0; t < 2; ++t) {
                int rb = wc * 32 + t * 16 + (lane & 15);
                int ch = kk * 4 + (lane >> 4);
                bfh[t] = *tchunk(lds + 16384, rb, ch);
                bfl[t] = *tchunk(lds + 20480, rb, ch);
            }
#pragma unroll
            for (int tm = 0; tm < 4; ++tm)
#pragma unroll
                for (int tn = 0; tn < 2; ++tn) {
                    acc[tm][tn] = __builtin_amdgcn_mfma_f32_16x16x32_bf16(
                        afh[tm], bfh[tn], acc[tm][tn], 0, 0, 0);
                    acc[tm][tn] = __builtin_amdgcn_mfma_f32_16x16x32_bf16(
                        afh[tm], bfl[tn], acc[tm][tn], 0, 0, 0);
                    acc[tm][tn] = __builtin_amdgcn_mfma_f32_16x16x32_bf16(
                        afl[tm], bfh[tn], acc[tm][tn], 0, 0, 0);
                }
        }
        __syncthreads();
    }
#pragma unroll
    for (int tm = 0; tm < 4; ++tm)
#pragma unroll
        for (int tn = 0; tn < 2; ++tn)
#pragma unroll
            for (int r = 0; r < 4; ++r) {
                int row = m0 + wr * 64 + tm * 16 + (lane >> 4) * 4 + r;
                int col = n0 + wc * 32 + tn * 16 + (lane & 15);
                C[(long)row * 1024 + col] = acc[tm][tn][r] + bias[col];
            }
}

// ---------------------------------------------------------------------------
extern "C" void kernel_launch(void* const* d_in, const int* in_sizes, int n_in,
                              void* d_out, int out_size, void* d_ws, size_t ws_size,
                              hipStream_t stream)
{
    const float* x     = (const float*)d_in[0];
    const float* Wq    = (const float*)d_in[1];
    const float* Wk    = (const float*)d_in[2];
    const float* Wv    = (const float*)d_in[3];
    const float* Wkmap = (const float*)d_in[4];
    const float* bkmap = (const float*)d_in[5];
    const float* Wvmap = (const float*)d_in[6];
    const float* bvmap = (const float*)d_in[7];
    const float* Wc    = (const float*)d_in[8];
    const float* bc    = (const float*)d_in[9];
    float* out = (float*)d_out;

    char* ws = (char*)d_ws;
    const long MB = 1l << 20;
    float* q   = (float*)(ws + 0 * MB);        // 8MB
    float* k   = (float*)(ws + 8 * MB);        // 8MB
    float* v   = (float*)(ws + 16 * MB);       // 8MB
    bf16* xh   = (bf16*)(ws + 24 * MB);        // 4MB (dead after qkv)
    bf16* xl   = (bf16*)(ws + 28 * MB);        // 4MB
    bf16* wqh  = (bf16*)(ws + 32 * MB);        // 2MB each (dead after qkv)
    bf16* wql  = (bf16*)(ws + 34 * MB);
    bf16* wkh  = (bf16*)(ws + 36 * MB);
    bf16* wkl  = (bf16*)(ws + 38 * MB);
    bf16* wvh  = (bf16*)(ws + 40 * MB);
    bf16* wvl  = (bf16*)(ws + 42 * MB);
    bf16* Wm4  = (bf16*)(ws + 44 * MB);        // 2MB (dead after setfeat)
    // post-qkv overlays:
    float* Ktail = (float*)(ws + 24 * MB);     // 8MB over xh/xl
    float* Vtail = (float*)(ws + 32 * MB);     // 8MB over wq/wk
    float* KsetT = (float*)(ws + 40 * MB);     // 128KB over wvh
    float* Vset  = (float*)(ws + 41 * MB);     // 128KB
    bf16* atth   = (bf16*)(ws + 8 * MB);       // 4MB over k (dead after setfeat)
    bf16* attl   = (bf16*)(ws + 12 * MB);      // 4MB
    bf16* wch    = (bf16*)(ws + 44 * MB);      // 2MB over Wm4 (written after setfeat)
    bf16* wcl    = (bf16*)(ws + 46 * MB);      // 2MB

    presplit_all_kernel<<<2560, 256, 0, stream>>>(x, Wq, Wk, Wv, xh, xl,
                                                  wqh, wql, wkh, wkl, wvh, wvl);
    presplit_wmap_kernel<<<64, 256, 0, stream>>>(Wkmap, Wvmap, Wm4);
    qkv_kernel<<<dim3(24, 16), 256, 0, stream>>>(xh, xl, wqh, wql, wkh, wkl,
                                                 wvh, wvl, q);
    setfeat_kernel<<<256, 512, 0, stream>>>(k, v, Wm4, bkmap, bvmap,
                                            Ktail, Vtail, KsetT, Vset);
    presplit_wc_kernel<<<512, 256, 0, stream>>>(Wc, wch, wcl);
    attn_kernel<<<8192, 256, 0, stream>>>(q, KsetT, Vset, Ktail, Vtail, atth, attl);
    gemm_final_kernel<<<dim3(16, 16), 256, 0, stream>>>(atth, attl, wch, wcl, bc, out);
}

// Round 9
// 256.960 us; speedup vs baseline: 1.9389x; 1.0361x over previous
//
#include <hip/hip_runtime.h>
#include <hip/hip_bf16.h>
#include <math.h>

typedef __hip_bfloat16 bf16;
typedef __attribute__((ext_vector_type(8))) short short8;
typedef __attribute__((ext_vector_type(4))) float f32x4;

#define C_DIM 1024
#define NHEAD 16
#define HS 64

__device__ __forceinline__ float bf2f(bf16 x) { return __bfloat162float(x); }
__device__ __forceinline__ short bfbits(float x) {
    bf16 h = __float2bfloat16(x);
    return *reinterpret_cast<short*>(&h);
}

// Async global->LDS, 16B per lane. LDS dest is wave-uniform base + lane*16.
__device__ __forceinline__ void gl16(const void* g, void* l) {
    __builtin_amdgcn_global_load_lds(
        (const __attribute__((address_space(1))) unsigned int*)g,
        (__attribute__((address_space(3))) unsigned int*)l, 16, 0, 0);
}

// Split 8 consecutive floats into bf16 hi + bf16 lo (residual) short8s.
__device__ __forceinline__ void split8(const float* p, short8& h, short8& l) {
    float4 f0 = reinterpret_cast<const float4*>(p)[0];
    float4 f1 = reinterpret_cast<const float4*>(p)[1];
    float vals[8] = {f0.x, f0.y, f0.z, f0.w, f1.x, f1.y, f1.z, f1.w};
#pragma unroll
    for (int j = 0; j < 8; ++j) {
        bf16 hb = __float2bfloat16(vals[j]);
        float r = vals[j] - __bfloat162float(hb);
        h[j] = *reinterpret_cast<short*>(&hb);
        bf16 lb = __float2bfloat16(r);
        l[j] = *reinterpret_cast<short*>(&lb);
    }
}

// Swizzled-LDS fragment read: [rows][64] bf16 tile, 16B chunk slot = ch ^ (row&7).
__device__ __forceinline__ short8* tchunk(bf16* tile, int row, int ch) {
    return reinterpret_cast<short8*>(tile + row * 64 + (((ch) ^ (row & 7)) << 3));
}

// ---------------------------------------------------------------------------
// Pre-split x,Wq,Wk,Wv -> bf16 hi/lo, stored PRE-SWIZZLED (chunk bits [5:3] of
// the element index XOR'd with row&7, row = idx>>10). Grid 2560 x 256.
// ---------------------------------------------------------------------------
__global__ __launch_bounds__(256) void presplit_all_kernel(
    const float* __restrict__ x, const float* __restrict__ Wq,
    const float* __restrict__ Wk, const float* __restrict__ Wv,
    bf16* __restrict__ xh, bf16* __restrict__ xl,
    bf16* __restrict__ wqh, bf16* __restrict__ wql,
    bf16* __restrict__ wkh, bf16* __restrict__ wkl,
    bf16* __restrict__ wvh, bf16* __restrict__ wvl)
{
    int blk = blockIdx.x;
    const float* src; bf16 *dh, *dl; long off;
    if (blk < 1024)      { src = x;  dh = xh;  dl = xl;  off = (long)blk * 2048; }
    else if (blk < 1536) { src = Wq; dh = wqh; dl = wql; off = (long)(blk - 1024) * 2048; }
    else if (blk < 2048) { src = Wk; dh = wkh; dl = wkl; off = (long)(blk - 1536) * 2048; }
    else                 { src = Wv; dh = wvh; dl = wvl; off = (long)(blk - 2048) * 2048; }
    long p = off + threadIdx.x * 8;
    int j = (int)(((p >> 3) ^ (p >> 10)) & 7);
    long dp = (p & ~56l) | ((long)j << 3);
    short8 h8, l8;
    split8(&src[p], h8, l8);
    *reinterpret_cast<short8*>(&dh[dp]) = h8;
    *reinterpret_cast<short8*>(&dl[dp]) = l8;
}

// Pre-split Wc (pre-swizzled). Runs after setfeat (dest overlays Wm4).
__global__ __launch_bounds__(256) void presplit_wc_kernel(
    const float* __restrict__ Wc, bf16* __restrict__ wch, bf16* __restrict__ wcl)
{
    long p = (long)blockIdx.x * 2048 + threadIdx.x * 8;
    int j = (int)(((p >> 3) ^ (p >> 10)) & 7);
    long dp = (p & ~56l) | ((long)j << 3);
    short8 h8, l8;
    split8(&Wc[p], h8, l8);
    *reinterpret_cast<short8*>(&wch[dp]) = h8;
    *reinterpret_cast<short8*>(&wcl[dp]) = l8;
}

// ---------------------------------------------------------------------------
// Pre-split Wkmap/Wvmap -> Wm4[d][part][row][e] bf16 (part 0=Kh 1=Kl 2=Vh 3=Vl),
// pre-swizzled within each 64-elem row. Grid 64 (one block per d).
// ---------------------------------------------------------------------------
__global__ __launch_bounds__(256) void presplit_wmap_kernel(
    const float* __restrict__ WK, const float* __restrict__ WV, bf16* __restrict__ Wm4)
{
    int d = blockIdx.x;
    int row = threadIdx.x >> 2, e0 = (threadIdx.x & 3) * 16;
    int sw0 = (((e0 >> 3) + 0) ^ (row & 7)) & 7;
    int sw1 = (((e0 >> 3) + 1) ^ (row & 7)) & 7;
    const float* pk = &WK[(long)row * 4096 + d * 64 + e0];
    const float* pv = &WV[(long)row * 4096 + d * 64 + e0];
    long bKh = ((long)(d * 4 + 0) * 64 + row) * 64;
    long bKl = ((long)(d * 4 + 1) * 64 + row) * 64;
    long bVh = ((long)(d * 4 + 2) * 64 + row) * 64;
    long bVl = ((long)(d * 4 + 3) * 64 + row) * 64;
    short8 h8, l8;
    split8(pk, h8, l8);     *(short8*)&Wm4[bKh + sw0*8] = h8; *(short8*)&Wm4[bKl + sw0*8] = l8;
    split8(pk + 8, h8, l8); *(short8*)&Wm4[bKh + sw1*8] = h8; *(short8*)&Wm4[bKl + sw1*8] = l8;
    split8(pv, h8, l8);     *(short8*)&Wm4[bVh + sw0*8] = h8; *(short8*)&Wm4[bVl + sw0*8] = l8;
    split8(pv + 8, h8, l8); *(short8*)&Wm4[bVh + sw1*8] = h8; *(short8*)&Wm4[bVl + sw1*8] = l8;
}

// ---------------------------------------------------------------------------
// Fused QKV GEMM; staging via global_load_lds from pre-swizzled operands.
// ---------------------------------------------------------------------------
__global__ __launch_bounds__(256) void qkv_kernel(
    const bf16* __restrict__ xh, const bf16* __restrict__ xl,
    const bf16* __restrict__ wqh, const bf16* __restrict__ wql,
    const bf16* __restrict__ wkh, const bf16* __restrict__ wkl,
    const bf16* __restrict__ wvh, const bf16* __restrict__ wvl,
    float* __restrict__ qkv)
{
    __shared__ bf16 lds[32768];   // Ah 0 | Al 8192 | Bh 16384 | Bl 24576 (elems)
    const int tid = threadIdx.x;
    const int lane = tid & 63, wid = tid >> 6;
    const int wr = wid >> 1, wc = wid & 1;
    const int proj = blockIdx.x >> 3;
    const int n0 = (blockIdx.x & 7) * 128;
    const int m0 = blockIdx.y * 128;
    const bf16* Bhp = proj == 0 ? wqh : (proj == 1 ? wkh : wvh);
    const bf16* Blp = proj == 0 ? wql : (proj == 1 ? wkl : wvl);
    float* C = qkv + (long)proj * 2097152;
    char* lb = reinterpret_cast<char*>(lds);

    f32x4 acc[4][4] = {};
    for (int kt = 0; kt < 16; ++kt) {
        const int k0 = kt << 6;
#pragma unroll
        for (int i = 0; i < 4; ++i) {
            int cc = tid + i * 256;             // 1024 chunks per tile
            int row = cc >> 3, j = cc & 7;
            long soA = (long)(m0 + row) * 1024 + k0 + j * 8;
            long soB = (long)(n0 + row) * 1024 + k0 + j * 8;
            gl16(&xh[soA],  lb + cc * 16);
            gl16(&xl[soA],  lb + 16384 + cc * 16);
            gl16(&Bhp[soB], lb + 32768 + cc * 16);
            gl16(&Blp[soB], lb + 49152 + cc * 16);
        }
        __syncthreads();
#pragma unroll
        for (int kk = 0; kk < 2; ++kk) {
            short8 afh[4], afl[4], bfh[4], bfl[4];
#pragma unroll
            for (int t = 0; t < 4; ++t) {
                int ra = wr * 64 + t * 16 + (lane & 15);
                int rb = wc * 64 + t * 16 + (lane & 15);
                int ch = kk * 4 + (lane >> 4);
                afh[t] = *tchunk(lds, ra, ch);
                afl[t] = *tchunk(lds + 8192, ra, ch);
                bfh[t] = *tchunk(lds + 16384, rb, ch);
                bfl[t] = *tchunk(lds + 24576, rb, ch);
            }
#pragma unroll
            for (int tm = 0; tm < 4; ++tm)
#pragma unroll
                for (int tn = 0; tn < 4; ++tn) {
                    acc[tm][tn] = __builtin_amdgcn_mfma_f32_16x16x32_bf16(
                        afh[tm], bfh[tn], acc[tm][tn], 0, 0, 0);
                    acc[tm][tn] = __builtin_amdgcn_mfma_f32_16x16x32_bf16(
                        afh[tm], bfl[tn], acc[tm][tn], 0, 0, 0);
                    acc[tm][tn] = __builtin_amdgcn_mfma_f32_16x16x32_bf16(
                        afl[tm], bfh[tn], acc[tm][tn], 0, 0, 0);
                }
        }
        __syncthreads();
    }
#pragma unroll
    for (int tm = 0; tm < 4; ++tm)
#pragma unroll
        for (int tn = 0; tn < 4; ++tn)
#pragma unroll
            for (int r = 0; r < 4; ++r) {
                int row = m0 + wr * 64 + tm * 16 + (lane >> 4) * 4 + r;
                int col = n0 + wc * 64 + tn * 16 + (lane & 15);
                float v = acc[tm][tn][r];
                if (proj < 2) v = v > 0.f ? v + 1.f : __expf(v);
                C[(long)row * 1024 + col] = v;
            }
}

// ---------------------------------------------------------------------------
// setfeat v6: counted-vmcnt pipeline. Loop = {s_barrier; issue stage(d+1);
// vmcnt(4); compute(d)} -- no full drain in the loop. 2-pass numerics:
// G_d = bf16(v) . (Wh + Wl)  (dropped v_lo term ~2^-9 relative).
// ---------------------------------------------------------------------------
__global__ __launch_bounds__(512) void setfeat_kernel(
    const float* __restrict__ kbuf, const float* __restrict__ vbuf,
    const bf16* __restrict__ Wm4,
    const float* __restrict__ bkmap, const float* __restrict__ bvmap,
    float* __restrict__ Ktail, float* __restrict__ Vtail,
    float* __restrict__ KsetT, float* __restrict__ Vset)
{
    __shared__ char smem[98304];
    bf16* W0 = reinterpret_cast<bf16*>(smem);            // 32KB
    bf16* W1 = reinterpret_cast<bf16*>(smem + 32768);    // 32KB
    const int tid = threadIdx.x;
    const int grp = tid >> 8;                   // 0/1: which (b,h) pair
    const int tl = tid & 255;
    const int lane = tl & 63, wid = tl >> 6;
    const int wr = wid >> 1, wc = wid & 1;
    const int pairIdx = blockIdx.x * 2 + grp;
    const int b = pairIdx >> 4, h = pairIdx & 15;
    const long base_kv = ((long)b * 64) * C_DIM + h * HS;
    float* kT = reinterpret_cast<float*>(smem + 65536 + grp * 16384); // kT[c][s]

    {   // stage kT[c][s] = k[s][c] (per group)
        int s = tl >> 2, cg = tl & 3;
        const float* src = &kbuf[base_kv + (long)s * C_DIM + cg * 16];
        float f[16];
#pragma unroll
        for (int j = 0; j < 4; ++j)
            *reinterpret_cast<float4*>(&f[j * 4]) = reinterpret_cast<const float4*>(src)[j];
#pragma unroll
        for (int j = 0; j < 16; ++j)
            kT[(cg * 16 + j) * 64 + s] = f[j];
    }
    // v fragments (loop-invariant A operand), rounded to bf16 in registers
    short8 vh[2][2];
#pragma unroll
    for (int tm = 0; tm < 2; ++tm)
#pragma unroll
        for (int kk = 0; kk < 2; ++kk) {
            const float* vp = &vbuf[base_kv +
                (long)(wr * 32 + tm * 16 + (lane & 15)) * C_DIM + kk * 32 + (lane >> 4) * 8];
            float4 f0 = reinterpret_cast<const float4*>(vp)[0];
            float4 f1 = reinterpret_cast<const float4*>(vp)[1];
            float vals[8] = {f0.x, f0.y, f0.z, f0.w, f1.x, f1.y, f1.z, f1.w};
#pragma unroll
            for (int j = 0; j < 8; ++j) vh[tm][kk][j] = bfbits(vals[j]);
        }
    // prologue: stage W chunk for d=0 into W0
#pragma unroll
    for (int i = 0; i < 4; ++i) {
        int cc = tid + i * 512;
        gl16(&Wm4[(long)cc * 8], smem + (long)cc * 16);
    }
    f32x4 accK[2][2] = {}, accV[2][2] = {};
    __syncthreads();   // full drain: stage(0) complete, kT visible

    for (int d = 0; d < 64; ++d) {
        bf16* Wcur = (d & 1) ? W1 : W0;
        char* Wnxt = (d & 1) ? smem : smem + 32768;
        __builtin_amdgcn_s_barrier();   // all waves done compute(d-1); buffer safe
        if (d < 63) {
#pragma unroll
            for (int i = 0; i < 4; ++i) {
                int cc = tid + i * 512;
                gl16(&Wm4[(long)(d + 1) * 16384 + (long)cc * 8], Wnxt + (long)cc * 16);
            }
            asm volatile("s_waitcnt vmcnt(4)" ::: "memory");  // stage(d) landed
        } else {
            asm volatile("s_waitcnt vmcnt(0)" ::: "memory");
        }
        f32x4 GK[2][2] = {}, GV[2][2] = {};
#pragma unroll
        for (int kk = 0; kk < 2; ++kk) {
            short8 bkh[2], bkl[2], bvh[2], bvl[2];
#pragma unroll
            for (int t = 0; t < 2; ++t) {
                int rb = wc * 32 + t * 16 + (lane & 15);
                int ch = kk * 4 + (lane >> 4);
                bkh[t] = *tchunk(Wcur,         rb, ch);
                bkl[t] = *tchunk(Wcur + 4096,  rb, ch);
                bvh[t] = *tchunk(Wcur + 8192,  rb, ch);
                bvl[t] = *tchunk(Wcur + 12288, rb, ch);
            }
#pragma unroll
            for (int tm = 0; tm < 2; ++tm)
#pragma unroll
                for (int tn = 0; tn < 2; ++tn) {
                    GK[tm][tn] = __builtin_amdgcn_mfma_f32_16x16x32_bf16(
                        vh[tm][kk], bkh[tn], GK[tm][tn], 0, 0, 0);
                    GK[tm][tn] = __builtin_amdgcn_mfma_f32_16x16x32_bf16(
                        vh[tm][kk], bkl[tn], GK[tm][tn], 0, 0, 0);
                    GV[tm][tn] = __builtin_amdgcn_mfma_f32_16x16x32_bf16(
                        vh[tm][kk], bvh[tn], GV[tm][tn], 0, 0, 0);
                    GV[tm][tn] = __builtin_amdgcn_mfma_f32_16x16x32_bf16(
                        vh[tm][kk], bvl[tn], GV[tm][tn], 0, 0, 0);
                }
        }
        // combine: out[s,i] += k[s,d] * G_d[s,i]
#pragma unroll
        for (int tm = 0; tm < 2; ++tm) {
            f32x4 kv = *reinterpret_cast<const f32x4*>(
                &kT[d * 64 + wr * 32 + tm * 16 + (lane >> 4) * 4]);
#pragma unroll
            for (int tn = 0; tn < 2; ++tn)
#pragma unroll
                for (int r = 0; r < 4; ++r) {
                    accK[tm][tn][r] += kv[r] * GK[tm][tn][r];
                    accV[tm][tn][r] += kv[r] * GV[tm][tn][r];
                }
        }
    }
    __syncthreads();   // all waves done reading W1/kT before Wall overlay writes
    // per-pair Wall overlays: pair0 [0,32KB), pair1 [32KB,64KB)
    float(*WallK)[64] = reinterpret_cast<float(*)[64]>(smem + grp * 32768);
    float(*WallV)[64] = reinterpret_cast<float(*)[64]>(smem + grp * 32768 + 16384);
#pragma unroll
    for (int tm = 0; tm < 2; ++tm)
#pragma unroll
        for (int tn = 0; tn < 2; ++tn)
#pragma unroll
            for (int r = 0; r < 4; ++r) {
                int row = wr * 32 + tm * 16 + (lane >> 4) * 4 + r;
                int col = wc * 32 + tn * 16 + (lane & 15);
                WallK[row][col] = accK[tm][tn][r];
                WallV[row][col] = accV[tm][tn][r];
            }
    __syncthreads();
    if (tl < 128) {
        int i = tl & 63;
        bool isV = tl >= 64;
        const float bi = isV ? bvmap[i] : bkmap[i];
        float run = 0.f;
        for (int s = 0; s < 64; ++s) {
            run += isV ? WallV[s][i] : WallK[s][i];
            float val = run + bi;
            long t = (long)b * 64 + s;
            if (isV) Vtail[t * C_DIM + h * HS + i] = val;
            else     Ktail[t * C_DIM + h * HS + i] = val;
            if (s == 63) {
                if (isV) Vset[(b * NHEAD + h) * HS + i] = val;
                else     KsetT[h * 2048 + i * 32 + b] = val;  // transposed [h][d][b]
            }
        }
    }
}

// ---------------------------------------------------------------------------
// Attention: one wave per (t,h). Tail logit wave-parallel; set-dot reads
// KsetT[h][d][s] (lane s consecutive -> coalesced). Writes pre-swizzled hi/lo.
// ---------------------------------------------------------------------------
__global__ __launch_bounds__(256) void attn_kernel(
    const float* __restrict__ qbuf, const float* __restrict__ KsetT,
    const float* __restrict__ Vset, const float* __restrict__ Ktail,
    const float* __restrict__ Vtail, bf16* __restrict__ atth, bf16* __restrict__ attl)
{
    __shared__ float qsh[4][64];
    __shared__ float attsh[4][64];
    const int tid = threadIdx.x, lane = tid & 63, wid = tid >> 6;
    const int g = blockIdx.x * 4 + wid;
    const int t = g >> 4, h = g & 15;
    const int nb = t >> 6;
    const float scale = 0.125f;
    const long qoff = (long)t * C_DIM + h * HS;
    float qv = qbuf[qoff + lane];
    qsh[wid][lane] = qv;
    // tail logit: wave-parallel dot + reduce (all lanes get sum)
    float tp = qv * Ktail[qoff + lane];
    for (int off = 32; off; off >>= 1) tp += __shfl_xor(tp, off, 64);
    __syncthreads();
    float logit = -INFINITY;
    if (lane < nb) {
        float s = 0.f;
        const float* Kp = &KsetT[h * 2048 + lane];     // + d*32
        for (int d = 0; d < 64; ++d) s += qsh[wid][d] * Kp[d * 32];
        logit = s * scale;
    } else if (lane == nb) {
        logit = tp * scale;
    }
    float m = logit;
    for (int off = 32; off; off >>= 1) m = fmaxf(m, __shfl_xor(m, off, 64));
    float e = (lane <= nb) ? __expf(logit - m) : 0.f;
    float sum = e;
    for (int off = 32; off; off >>= 1) sum += __shfl_xor(sum, off, 64);
    attsh[wid][lane] = e / sum;
    __syncthreads();
    float out = 0.f;
    for (int s = 0; s < nb; ++s)
        out += attsh[wid][s] * Vset[(s * NHEAD + h) * HS + lane];
    out += attsh[wid][nb] * Vtail[qoff + lane];
    bf16 hb = __float2bfloat16(out);
    int csw = (((lane >> 3) ^ (t & 7)) << 3) | (lane & 7);
    long po = (long)t * 1024 + h * 64 + csw;
    atth[po] = hb;
    attl[po] = __float2bfloat16(out - bf2f(hb));
}

// ---------------------------------------------------------------------------
// Final GEMM: out = attout @ Wc^T + bc. 128x64 tiles, global_load_lds staging.
// ---------------------------------------------------------------------------
__global__ __launch_bounds__(256) void gemm_final_kernel(
    const bf16* __restrict__ ah, const bf16* __restrict__ al,
    const bf16* __restrict__ bh, const bf16* __restrict__ bl,
    const float* __restrict__ bias, float* __restrict__ C)
{
    __shared__ bf16 lds[24576];   // Ah 0 | Al 8192 | Bh 16384 | Bl 20480 (elems)
    const int tid = threadIdx.x;
    const int lane = tid & 63, wid = tid >> 6;
    const int wr = wid >> 1, wc = wid & 1;
    const int m0 = blockIdx.y * 128, n0 = blockIdx.x * 64;
    char* lb = reinterpret_cast<char*>(lds);

    f32x4 acc[4][2] = {};
    for (int kt = 0; kt < 16; ++kt) {
        const int k0 = kt << 6;
#pragma unroll
        for (int i = 0; i < 4; ++i) {
            int cc = tid + i * 256;
            int row = cc >> 3, j = cc & 7;
            long so = (long)(m0 + row) * 1024 + k0 + j * 8;
            gl16(&ah[so], lb + cc * 16);
            gl16(&al[so], lb + 16384 + cc * 16);
        }
#pragma unroll
        for (int i = 0; i < 2; ++i) {
            int cc = tid + i * 256;
            int row = cc >> 3, j = cc & 7;
            long so = (long)(n0 + row) * 1024 + k0 + j * 8;
            gl16(&bh[so], lb + 32768 + cc * 16);
            gl16(&bl[so], lb + 40960 + cc * 16);
        }
        __syncthreads();
#pragma unroll
        for (int kk = 0; kk < 2; ++kk) {
            short8 afh[4], afl[4], bfh[2], bfl[2];
#pragma unroll
            for (int t = 0; t < 4; ++t) {
                int ra = wr * 64 + t * 16 + (lane & 15);
                int ch = kk * 4 + (lane >> 4);
                afh[t] = *tchunk(lds, ra, ch);
                afl[t] = *tchunk(lds + 8192, ra, ch);
            }
#pragma unroll
            for (int t = 0; t < 2; ++t) {
                int rb = wc * 32 + t * 16 + (lane & 15);
                int ch = kk * 4 + (lane >> 4);
                bfh[t] = *tchunk(lds + 16384, rb, ch);
                bfl[t] = *tchunk(lds + 20480, rb, ch);
            }
#pragma unroll
            for (int tm = 0; tm < 4; ++tm)
#pragma unroll
                for (int tn = 0; tn < 2; ++tn) {
                    acc[tm][tn] = __builtin_amdgcn_mfma_f32_16x16x32_bf16(
                        afh[tm], bfh[tn], acc[tm][tn], 0, 0, 0);
                    acc[tm][tn] = __builtin_amdgcn_mfma_f32_16x16x32_bf16(
                        afh[tm], bfl[tn], acc[tm][tn], 0, 0, 0);
                    acc[tm][tn] = __builtin_amdgcn_mfma_f32_16x16x32_bf16(
                        afl[tm], bfh[tn], acc[tm][tn], 0, 0, 0);
                }
        }
        __syncthreads();
    }
#pragma unroll
    for (int tm = 0; tm < 4; ++tm)
#pragma unroll
        for (int tn = 0; tn < 2; ++tn)
#pragma unroll
            for (int r = 0; r < 4; ++r) {
                int row = m0 + wr * 64 + tm * 16 + (lane >> 4) * 4 + r;
                int col = n0 + wc * 32 + tn * 16 + (lane & 15);
                C[(long)row * 1024 + col] = acc[tm][tn][r] + bias[col];
            }
}

// ---------------------------------------------------------------------------
extern "C" void kernel_launch(void* const* d_in, const int* in_sizes, int n_in,
                              void* d_out, int out_size, void* d_ws, size_t ws_size,
                              hipStream_t stream)
{
    const float* x     = (const float*)d_in[0];
    const float* Wq    = (const float*)d_in[1];
    const float* Wk    = (const float*)d_in[2];
    const float* Wv    = (const float*)d_in[3];
    const float* Wkmap = (const float*)d_in[4];
    const float* bkmap = (const float*)d_in[5];
    const float* Wvmap = (const float*)d_in[6];
    const float* bvmap = (const float*)d_in[7];
    const float* Wc    = (const float*)d_in[8];
    const float* bc    = (const float*)d_in[9];
    float* out = (float*)d_out;

    char* ws = (char*)d_ws;
    const long MB = 1l << 20;
    float* q   = (float*)(ws + 0 * MB);        // 8MB
    float* k   = (float*)(ws + 8 * MB);        // 8MB
    float* v   = (float*)(ws + 16 * MB);       // 8MB
    bf16* xh   = (bf16*)(ws + 24 * MB);        // 4MB (dead after qkv)
    bf16* xl   = (bf16*)(ws + 28 * MB);        // 4MB
    bf16* wqh  = (bf16*)(ws + 32 * MB);        // 2MB each (dead after qkv)
    bf16* wql  = (bf16*)(ws + 34 * MB);
    bf16* wkh  = (bf16*)(ws + 36 * MB);
    bf16* wkl  = (bf16*)(ws + 38 * MB);
    bf16* wvh  = (bf16*)(ws + 40 * MB);
    bf16* wvl  = (bf16*)(ws + 42 * MB);
    bf16* Wm4  = (bf16*)(ws + 44 * MB);        // 2MB (dead after setfeat)
    // post-qkv overlays:
    float* Ktail = (float*)(ws + 24 * MB);     // 8MB over xh/xl
    float* Vtail = (float*)(ws + 32 * MB);     // 8MB over wq/wk
    float* KsetT = (float*)(ws + 40 * MB);     // 128KB over wvh
    float* Vset  = (float*)(ws + 41 * MB);     // 128KB
    bf16* atth   = (bf16*)(ws + 8 * MB);       // 4MB over k (dead after setfeat)
    bf16* attl   = (bf16*)(ws + 12 * MB);      // 4MB
    bf16* wch    = (bf16*)(ws + 44 * MB);      // 2MB over Wm4 (written after setfeat)
    bf16* wcl    = (bf16*)(ws + 46 * MB);      // 2MB

    presplit_all_kernel<<<2560, 256, 0, stream>>>(x, Wq, Wk, Wv, xh, xl,
                                                  wqh, wql, wkh, wkl, wvh, wvl);
    presplit_wmap_kernel<<<64, 256, 0, stream>>>(Wkmap, Wvmap, Wm4);
    qkv_kernel<<<dim3(24, 16), 256, 0, stream>>>(xh, xl, wqh, wql, wkh, wkl,
                                                 wvh, wvl, q);
    setfeat_kernel<<<256, 512, 0, stream>>>(k, v, Wm4, bkmap, bvmap,
                                            Ktail, Vtail, KsetT, Vset);
    presplit_wc_kernel<<<512, 256, 0, stream>>>(Wc, wch, wcl);
    attn_kernel<<<8192, 256, 0, stream>>>(q, KsetT, Vset, Ktail, Vtail, atth, attl);
    gemm_final_kernel<<<dim3(16, 16), 256, 0, stream>>>(atth, attl, wch, wcl, bc, out);
}